// Round 13
// baseline (373.963 us; speedup 1.0000x reference)
//
#include <hip/hip_runtime.h>
#include <cmath>

// HyperKGL: N=100000, H=20000, NS=10, D=64, L=2, E=1e6, NB=50000
// R12 -> R13: (1) scatter: 4 windows (halve rec re-scan) + grid 2048 (2x waves
// for atomic latency hiding). (2) k_rowmatB deleted: hq=he@Wa computed per-hed
// inside attention (wave matvec, Wa from L2); sema@Wm as per-block prologue.

#define EPSF 1e-9f
#define NSLOT 40960
#define SENT 0xFFFFFFFFu
#define ATP 68
typedef unsigned long long ull;

__device__ __forceinline__ float group16_sum(float v){
  v += __shfl_xor(v, 1, 64);
  v += __shfl_xor(v, 2, 64);
  v += __shfl_xor(v, 4, 64);
  v += __shfl_xor(v, 8, 64);
  return v;
}
__device__ __forceinline__ float xgroup_sum(float v){
  v += __shfl_xor(v, 16, 64);
  v += __shfl_xor(v, 32, 64);
  return v;
}
__device__ __forceinline__ unsigned short f2bf(float f){
  unsigned b = __float_as_uint(f);
  unsigned r = (b + 0x7FFFu + ((b >> 16) & 1u)) >> 16;
  return (unsigned short)r;
}
__device__ __forceinline__ float bf2f(unsigned short u){
  return __uint_as_float(((unsigned)u) << 16);
}

// ---------------- setup ----------------
__global__ __launch_bounds__(256) void k_copy4(const float4* __restrict__ in, float4* __restrict__ out, int n){
  int i = blockIdx.x*256 + threadIdx.x;
  if (i < n) out[i] = in[i];
}

__global__ __launch_bounds__(256) void k_set_member(const int* __restrict__ idx, int* __restrict__ member, int n){
  int i = blockIdx.x*256 + threadIdx.x;
  if (i < n) member[idx[i]] = 1;
}

__global__ __launch_bounds__(256) void k_build_list(int* __restrict__ member, int* __restrict__ mlist,
                                                    int* __restrict__ mcount, int N){
  int n = blockIdx.x*256 + threadIdx.x;
  if (n < N && member[n]) {
    int p = atomicAdd(mcount, 1);
    mlist[p] = n;
    member[n] = p + 2;   // slot+2 (0 = non-member)
  }
}

// record build + per-key degree counts in one streaming pass
__global__ __launch_bounds__(256) void k_count_rec(const int* __restrict__ sl, const int* __restrict__ member,
    ull* __restrict__ rec, int* __restrict__ cnt_hed, int* __restrict__ cnt_slot, int E){
  int e = blockIdx.x*256 + threadIdx.x;
  if (e >= E) return;
  int src = sl[3*e];
  int m = member[src];
  if (m){
    int slot = m - 2;
    int hed = sl[3*e+1];
    int sem = sl[3*e+2];
    unsigned lo = (unsigned)slot | ((unsigned)sem << 20);
    rec[e] = (ull)lo | ((ull)(unsigned)hed << 32);
    atomicAdd(&cnt_hed[hed], 1);
    atomicAdd(&cnt_slot[slot], 1);
  } else {
    rec[e] = (ull)SENT << 32;
  }
}

__global__ __launch_bounds__(256) void k_scan1(const int* __restrict__ in, int* __restrict__ out, int n,
                                               int* __restrict__ partials){
  __shared__ int s[256];
  int b = blockIdx.x, t = threadIdx.x;
  int base = b*2048 + t*8;
  int v[8]; int sum = 0;
  #pragma unroll
  for (int j=0;j<8;j++){ int i = base + j; v[j] = (i<n) ? in[i] : 0; sum += v[j]; }
  s[t] = sum;
  __syncthreads();
  for (int o=1;o<256;o<<=1){
    int x = (t>=o) ? s[t-o] : 0;
    __syncthreads();
    s[t] += x;
    __syncthreads();
  }
  int excl = s[t] - sum;
  if (t == 255) partials[b] = s[255];
  int run = excl;
  #pragma unroll
  for (int j=0;j<8;j++){ int i = base + j; if (i<n) out[i] = run; run += v[j]; }
}

__global__ void k_scan2(int* __restrict__ partials, int nb, int* __restrict__ out, int n){
  if (threadIdx.x==0 && blockIdx.x==0){
    int run = 0;
    for (int i=0;i<nb;i++){ int x = partials[i]; partials[i] = run; run += x; }
    out[n] = run;
  }
}

__global__ __launch_bounds__(256) void k_scan3(int* __restrict__ out, const int* __restrict__ partials, int n){
  int i = blockIdx.x*256 + threadIdx.x;
  if (i < n) out[i] += partials[i >> 11];
}

// merged windowed scatter, 4 windows (window = blockIdx&3)
__global__ __launch_bounds__(256) void k_scatter_both(const ull* __restrict__ rec,
    const int* __restrict__ mcountp,
    const int* __restrict__ off_hed, int* __restrict__ cur_hed, unsigned* __restrict__ edge_hed,
    const int* __restrict__ off_slot, int* __restrict__ cur_slot, unsigned* __restrict__ edge_src, int E){
  int w = blockIdx.x & 3;
  int chunk = blockIdx.x >> 2;
  int nchunk = gridDim.x >> 2;
  int per = (E + nchunk - 1) / nchunk;
  int lo_i = chunk * per;
  int hi_i = min(E, lo_i + per);
  int divs = (*mcountp + 3) >> 2;
  for (int i = lo_i + threadIdx.x; i < hi_i; i += 256){
    ull r = rec[i];
    unsigned hed = (unsigned)(r >> 32);
    if (hed == SENT) continue;
    unsigned lo = (unsigned)r;
    int slot = lo & 0xFFFFF;
    if ((int)hed / 5000 == w){
      int p = off_hed[hed] + atomicAdd(&cur_hed[hed], 1);
      edge_hed[p] = lo;
    }
    if (slot / divs == w){
      int p = off_slot[slot] + atomicAdd(&cur_slot[slot], 1);
      edge_src[p] = hed | (lo & 0xFFF00000u);
    }
  }
}

// ================= 4x4 register-blocked GEMM64 =================
#define LOAD_W(Wl, Wsrc) for (int i_=threadIdx.x; i_<1024; i_+=256) ((float4*)Wl)[i_] = ((const float4*)(Wsrc))[i_];

#define STAGE_AT(At, ro, nrows, LOADEXPR)                              \
  {                                                                    \
    int cg_ = threadIdx.x & 15, rl_ = threadIdx.x >> 4;                \
    for (int p_ = 0; p_ < 4; ++p_){                                    \
      int rloc_ = p_*16 + rl_;                                         \
      int r_ = (ro) + rloc_;                                           \
      float4 v_ = make_float4(0.f,0.f,0.f,0.f);                        \
      if (r_ < (nrows)){ v_ = (LOADEXPR); }                            \
      At[cg_*4+0][rloc_] = v_.x;                                       \
      At[cg_*4+1][rloc_] = v_.y;                                       \
      At[cg_*4+2][rloc_] = v_.z;                                       \
      At[cg_*4+3][rloc_] = v_.w;                                       \
    }                                                                  \
  }

__device__ __forceinline__ void gemm44(const float* __restrict__ Wl, const float (*At)[ATP],
                                       int rg4, int cg4, float4 acc[4]){
  #pragma unroll 8
  for (int k = 0; k < 64; ++k){
    const float4 w = *(const float4*)&Wl[k*64 + cg4];
    const float4 a = *(const float4*)&At[k][rg4];
    acc[0].x = fmaf(a.x,w.x,acc[0].x); acc[0].y = fmaf(a.x,w.y,acc[0].y);
    acc[0].z = fmaf(a.x,w.z,acc[0].z); acc[0].w = fmaf(a.x,w.w,acc[0].w);
    acc[1].x = fmaf(a.y,w.x,acc[1].x); acc[1].y = fmaf(a.y,w.y,acc[1].y);
    acc[1].z = fmaf(a.y,w.z,acc[1].z); acc[1].w = fmaf(a.y,w.w,acc[1].w);
    acc[2].x = fmaf(a.z,w.x,acc[2].x); acc[2].y = fmaf(a.z,w.y,acc[2].y);
    acc[2].z = fmaf(a.z,w.z,acc[2].z); acc[2].w = fmaf(a.z,w.w,acc[2].w);
    acc[3].x = fmaf(a.w,w.x,acc[3].x); acc[3].y = fmaf(a.w,w.y,acc[3].y);
    acc[3].z = fmaf(a.w,w.z,acc[3].z); acc[3].w = fmaf(a.w,w.w,acc[3].w);
  }
}

#define ZERO4(a) { a[0]=make_float4(0,0,0,0); a[1]=make_float4(0,0,0,0); a[2]=make_float4(0,0,0,0); a[3]=make_float4(0,0,0,0); }

// rowmatA: nm_bf = bf16(ne[mlist]@Wm) ; inner1 = ne[mlist]@Wi1
__global__ __launch_bounds__(256) void k_rowmatA(const float* __restrict__ ne, const float* __restrict__ Wm,
    const float* __restrict__ Wi1, const int* __restrict__ mlist, const int* __restrict__ mcountp,
    unsigned short* __restrict__ nm_bf, float* __restrict__ inner1){
  __shared__ float W1[4096], W2[4096];
  __shared__ float At[64][ATP];
  int t = threadIdx.x;
  int nrows = *mcountp;
  int ntiles = (nrows + 63) >> 6;
  LOAD_W(W1, Wm)
  LOAD_W(W2, Wi1)
  int cg4 = (t & 15)*4, rg4 = (t >> 4)*4;
  for (int tile = blockIdx.x; tile < ntiles; tile += gridDim.x){
    int ro = tile << 6;
    __syncthreads();
    STAGE_AT(At, ro, nrows, (*(const float4*)&ne[(size_t)mlist[r_]*64 + cg_*4]))
    __syncthreads();
    float4 a1[4]; ZERO4(a1)
    float4 a2[4]; ZERO4(a2)
    #pragma unroll 4
    for (int k = 0; k < 64; ++k){
      const float4 w1 = *(const float4*)&W1[k*64 + cg4];
      const float4 w2 = *(const float4*)&W2[k*64 + cg4];
      const float4 a  = *(const float4*)&At[k][rg4];
      a1[0].x=fmaf(a.x,w1.x,a1[0].x); a1[0].y=fmaf(a.x,w1.y,a1[0].y); a1[0].z=fmaf(a.x,w1.z,a1[0].z); a1[0].w=fmaf(a.x,w1.w,a1[0].w);
      a1[1].x=fmaf(a.y,w1.x,a1[1].x); a1[1].y=fmaf(a.y,w1.y,a1[1].y); a1[1].z=fmaf(a.y,w1.z,a1[1].z); a1[1].w=fmaf(a.y,w1.w,a1[1].w);
      a1[2].x=fmaf(a.z,w1.x,a1[2].x); a1[2].y=fmaf(a.z,w1.y,a1[2].y); a1[2].z=fmaf(a.z,w1.z,a1[2].z); a1[2].w=fmaf(a.z,w1.w,a1[2].w);
      a1[3].x=fmaf(a.w,w1.x,a1[3].x); a1[3].y=fmaf(a.w,w1.y,a1[3].y); a1[3].z=fmaf(a.w,w1.z,a1[3].z); a1[3].w=fmaf(a.w,w1.w,a1[3].w);
      a2[0].x=fmaf(a.x,w2.x,a2[0].x); a2[0].y=fmaf(a.x,w2.y,a2[0].y); a2[0].z=fmaf(a.x,w2.z,a2[0].z); a2[0].w=fmaf(a.x,w2.w,a2[0].w);
      a2[1].x=fmaf(a.y,w2.x,a2[1].x); a2[1].y=fmaf(a.y,w2.y,a2[1].y); a2[1].z=fmaf(a.y,w2.z,a2[1].z); a2[1].w=fmaf(a.y,w2.w,a2[1].w);
      a2[2].x=fmaf(a.z,w2.x,a2[2].x); a2[2].y=fmaf(a.z,w2.y,a2[2].y); a2[2].z=fmaf(a.z,w2.z,a2[2].z); a2[2].w=fmaf(a.z,w2.w,a2[2].w);
      a2[3].x=fmaf(a.w,w2.x,a2[3].x); a2[3].y=fmaf(a.w,w2.y,a2[3].y); a2[3].z=fmaf(a.w,w2.z,a2[3].z); a2[3].w=fmaf(a.w,w2.w,a2[3].w);
    }
    #pragma unroll
    for (int i = 0; i < 4; ++i){
      int r = ro + rg4 + i;
      if (r < nrows){
        ushort4 s;
        s.x = f2bf(a1[i].x); s.y = f2bf(a1[i].y); s.z = f2bf(a1[i].z); s.w = f2bf(a1[i].w);
        *(ushort4*)&nm_bf[(size_t)r*64 + cg4] = s;
        *(float4*)&inner1[(size_t)r*64 + cg4] = a2[i];
      }
    }
  }
}

// matfuse (unchanged)
__global__ __launch_bounds__(256) void k_matfuse(const float* __restrict__ inner1, const float* __restrict__ nagg,
    const float* __restrict__ oagg, const float* __restrict__ Wi2, const float* __restrict__ Wn,
    const float* __restrict__ We, const float* __restrict__ Ws,
    const int* __restrict__ mlist, const int* __restrict__ mcountp, float* __restrict__ ne){
  __shared__ float Wl[4096];
  __shared__ float At[64][ATP];
  int t = threadIdx.x;
  int cnt = *mcountp;
  int ntiles = (cnt + 63) >> 6;
  int cg4 = (t & 15)*4, rg4 = (t >> 4)*4;
  for (int tile = blockIdx.x; tile < ntiles; tile += gridDim.x){
    int ro = tile << 6;
    __syncthreads();
    STAGE_AT(At, ro, cnt, (*(const float4*)&nagg[(size_t)r_*64 + cg_*4]))
    LOAD_W(Wl, Ws)
    __syncthreads();
    float4 acc[4]; ZERO4(acc)
    gemm44(Wl, At, rg4, cg4, acc);   // acc = An@Ws
    __syncthreads();
    LOAD_W(Wl, Wi2)
    __syncthreads();
    float4 p1[4]; ZERO4(p1)
    gemm44(Wl, At, rg4, cg4, p1);    // p1 = An@Wi2
    float x[4][4];
    #pragma unroll
    for (int i = 0; i < 4; ++i){
      int r = ro + rg4 + i;
      float4 v = make_float4(0.f,0.f,0.f,0.f);
      if (r < cnt) v = *(const float4*)&inner1[(size_t)r*64 + cg4];
      float x0 = p1[i].x + v.x, x1 = p1[i].y + v.y, x2 = p1[i].z + v.z, x3 = p1[i].w + v.w;
      x[i][0] = x0 >= 0.f ? x0 : 0.01f*x0;
      x[i][1] = x1 >= 0.f ? x1 : 0.01f*x1;
      x[i][2] = x2 >= 0.f ? x2 : 0.01f*x2;
      x[i][3] = x3 >= 0.f ? x3 : 0.01f*x3;
    }
    __syncthreads();
    #pragma unroll
    for (int i = 0; i < 4; ++i)
      #pragma unroll
      for (int j = 0; j < 4; ++j)
        At[cg4+j][rg4+i] = x[i][j];
    LOAD_W(Wl, Wn)
    __syncthreads();
    gemm44(Wl, At, rg4, cg4, acc);   // acc += Ai@Wn
    __syncthreads();
    STAGE_AT(At, ro, cnt, (*(const float4*)&oagg[(size_t)r_*64 + cg_*4]))
    LOAD_W(Wl, We)
    __syncthreads();
    gemm44(Wl, At, rg4, cg4, acc);   // acc += Ao@We
    #pragma unroll
    for (int i = 0; i < 4; ++i){
      int r = ro + rg4 + i;
      if (r < cnt){
        float4 o = make_float4(tanhf(acc[i].x), tanhf(acc[i].y), tanhf(acc[i].z), tanhf(acc[i].w));
        *(float4*)&ne[(size_t)mlist[r]*64 + cg4] = o;
      }
    }
  }
}

// ---------------- attention + in-kernel hq/sm + W_upd matvec; bf16 nm gathers ----------------
__global__ __launch_bounds__(256) void k_attn_upd(const int* __restrict__ off_hed, const unsigned* __restrict__ edge_hed,
    const unsigned short* __restrict__ nm_bf, const float* __restrict__ sema, const float* __restrict__ Wm,
    const float* __restrict__ Wa, const float* __restrict__ W,
    const float* __restrict__ he_cur, float* __restrict__ he_next,
    unsigned short* __restrict__ he_bf, int H){
  __shared__ float Wl[4096];
  __shared__ float sm_lds[640];
  __shared__ float aggl[256];
  __shared__ float hrow[4][64];
  __shared__ float qh[4][64];
  int t = threadIdx.x;
  for (int i=t;i<1024;i+=256) ((float4*)Wl)[i] = ((const float4*)W)[i];
  if (t < 160){
    int sr = t >> 4, c4 = (t & 15)*4;
    float4 accs = make_float4(0,0,0,0);
    #pragma unroll 8
    for (int k = 0; k < 64; ++k){
      float a = sema[sr*64 + k];
      float4 wv = *(const float4*)&Wm[k*64 + c4];
      accs.x = fmaf(a,wv.x,accs.x); accs.y = fmaf(a,wv.y,accs.y);
      accs.z = fmaf(a,wv.z,accs.z); accs.w = fmaf(a,wv.w,accs.w);
    }
    *(float4*)&sm_lds[sr*64 + c4] = accs;
  }
  __syncthreads();
  int w = t >> 6, lane = t & 63;
  int nhb = (H + 3) >> 2;
  for (int hb = blockIdx.x; hb < nhb; hb += gridDim.x){
    int h = hb*4 + w;
    if (h >= H) continue;
    int start = off_hed[h], end = off_hed[h+1];
    if (start == end){
      float v = he_cur[(size_t)h*64 + lane];
      he_next[(size_t)h*64 + lane] = v;
      he_bf[(size_t)h*64 + lane] = f2bf(v);
      continue;
    }
    // q = he_cur[h] @ Wa, computed per wave (Wa from L2)
    hrow[w][lane] = he_cur[(size_t)h*64 + lane];
    float qv = 0.f;
    #pragma unroll 8
    for (int k = 0; k < 64; ++k) qv = fmaf(hrow[w][k], Wa[k*64 + lane], qv);
    qh[w][lane] = qv;
    int g = lane >> 4, dl = (lane & 15)*4;
    float4 q4 = *(const float4*)&qh[w][dl];
    float ax=0.f, ay=0.f, az=0.f, aw=0.f, dsum=0.f, m=-3.4e38f;
    for (int idx0 = start; idx0 < end; idx0 += 4){
      int idx = idx0 + g;
      bool valid = idx < end;
      unsigned u = valid ? edge_hed[idx] : 0u;
      int slot = u & 0xFFFFF, sem = u >> 20;
      float4 nm4 = make_float4(0.f,0.f,0.f,0.f);
      if (valid){
        ushort4 nu = *(const ushort4*)&nm_bf[(size_t)slot*64 + dl];
        nm4 = make_float4(bf2f(nu.x), bf2f(nu.y), bf2f(nu.z), bf2f(nu.w));
      }
      float4 sm4 = *(const float4*)&sm_lds[sem*64 + dl];
      float mkx = nm4.x+sm4.x, mky = nm4.y+sm4.y, mkz = nm4.z+sm4.z, mkw = nm4.w+sm4.w;
      float part = mkx*q4.x + mky*q4.y + mkz*q4.z + mkw*q4.w;
      part = group16_sum(part);
      float l = valid ? part : -3.4e38f;
      float mn = fmaxf(m, l);
      float scale = __expf(m - mn);
      float wgt = valid ? __expf(l - mn) : 0.f;
      ax = ax*scale + wgt*mkx; ay = ay*scale + wgt*mky;
      az = az*scale + wgt*mkz; aw = aw*scale + wgt*mkw;
      dsum = dsum*scale + wgt;
      m = mn;
    }
    float mg = fmaxf(m, __shfl_xor(m, 16, 64));
    mg = fmaxf(mg, __shfl_xor(mg, 32, 64));
    float cs = __expf(m - mg);
    ax*=cs; ay*=cs; az*=cs; aw*=cs; dsum*=cs;
    ax = xgroup_sum(ax); ay = xgroup_sum(ay); az = xgroup_sum(az); aw = xgroup_sum(aw);
    dsum = xgroup_sum(dsum);
    if (lane < 16){
      float inv = 1.f/(dsum + EPSF);
      aggl[w*64 + dl+0] = ax*inv;
      aggl[w*64 + dl+1] = ay*inv;
      aggl[w*64 + dl+2] = az*inv;
      aggl[w*64 + dl+3] = aw*inv;
    }
    float o = 0.f;
    #pragma unroll 8
    for (int j=0;j<64;j++) o = fmaf(aggl[w*64 + j], Wl[j*64 + lane], o);
    float ov = tanhf(o);
    he_next[(size_t)h*64 + lane] = ov;
    he_bf[(size_t)h*64 + lane] = f2bf(ov);
  }
}

// ---------------- per-member-slot aggregation; bf16 he gathers ----------------
__global__ __launch_bounds__(256) void k_nodeagg2(const int* __restrict__ mcountp,
    const int* __restrict__ off_slot, const unsigned* __restrict__ edge_src,
    const unsigned short* __restrict__ he_bf, const float* __restrict__ sema,
    float* __restrict__ nagg, float* __restrict__ oagg){
  __shared__ float sm_lds[640];
  int t = threadIdx.x;
  for (int i=t;i<640;i+=256) sm_lds[i] = sema[i];
  __syncthreads();
  int w = t >> 6, lane = t & 63;
  int mc = *mcountp;
  int npb = (mc + 3) >> 2;
  int g = lane >> 4, dl = (lane & 15)*4;
  for (int pb = blockIdx.x; pb < npb; pb += gridDim.x){
    int p = pb*4 + w;
    if (p >= mc) continue;
    int start = off_slot[p], end = off_slot[p+1];
    float anx=0.f, any_=0.f, anz=0.f, anw=0.f;
    float aox=0.f, aoy=0.f, aoz=0.f, aow=0.f;
    for (int idx0 = start; idx0 < end; idx0 += 4){
      int idx = idx0 + g;
      if (idx < end){
        unsigned u = edge_src[idx];
        int hd = u & 0xFFFFF, sem = u >> 20;
        ushort4 hu = *(const ushort4*)&he_bf[(size_t)hd*64 + dl];
        float4 hv = make_float4(bf2f(hu.x), bf2f(hu.y), bf2f(hu.z), bf2f(hu.w));
        float4 sv = *(const float4*)&sm_lds[sem*64 + dl];
        anx += hv.x; any_ += hv.y; anz += hv.z; anw += hv.w;
        aox = fmaf(hv.x, sv.x, aox); aoy = fmaf(hv.y, sv.y, aoy);
        aoz = fmaf(hv.z, sv.z, aoz); aow = fmaf(hv.w, sv.w, aow);
      }
    }
    anx = xgroup_sum(anx); any_ = xgroup_sum(any_); anz = xgroup_sum(anz); anw = xgroup_sum(anw);
    aox = xgroup_sum(aox); aoy = xgroup_sum(aoy); aoz = xgroup_sum(aoz); aow = xgroup_sum(aow);
    if (lane < 16){
      float inv = 1.f/((float)(end - start) + EPSF);
      *(float4*)&nagg[(size_t)p*64 + dl] = make_float4(anx*inv, any_*inv, anz*inv, anw*inv);
      *(float4*)&oagg[(size_t)p*64 + dl] = make_float4(aox*inv, aoy*inv, aoz*inv, aow*inv);
    }
  }
}

extern "C" void kernel_launch(void* const* d_in, const int* in_sizes, int n_in,
                              void* d_out, int out_size, void* d_ws, size_t ws_size,
                              hipStream_t stream)
{
  (void)in_sizes; (void)n_in; (void)out_size; (void)ws_size;
  const float* node_emb  = (const float*)d_in[0];
  const float* hyper_emb = (const float*)d_in[1];
  const float* sema_emb  = (const float*)d_in[2];
  const float* W_msg = (const float*)d_in[3];
  const float* W_att = (const float*)d_in[4];
  const float* W_upd = (const float*)d_in[5];
  const float* Wi1   = (const float*)d_in[6];
  const float* Wi2   = (const float*)d_in[7];
  const float* Wo_n  = (const float*)d_in[8];
  const float* Wo_e  = (const float*)d_in[9];
  const float* Wo_s  = (const float*)d_in[10];
  const int* node_indices = (const int*)d_in[11];
  const int* semalinks    = (const int*)d_in[14];

  constexpr int N = 100000, H = 20000, NS = 10, L = 2, E = 1000000, NB = 50000;
  (void)NS;

  float* out_ne = (float*)d_out;                    // N*64
  float* out_he = (float*)d_out + (size_t)N*64;     // H*64

  char* wsp = (char*)d_ws;
  auto alloc = [&](size_t bytes)->char*{ char* p = wsp; wsp += (bytes + 255) & ~(size_t)255; return p; };
  char* zstart = wsp;
  int* member   = (int*)alloc((size_t)N*4);
  int* cnt_hed  = (int*)alloc((size_t)H*4);
  int* cnt_slot = (int*)alloc((size_t)NSLOT*4);
  int* cur_hed  = (int*)alloc((size_t)H*4);
  int* cur_slot = (int*)alloc((size_t)NSLOT*4);
  int* mcount   = (int*)alloc(256);
  size_t zbytes = (size_t)(wsp - zstart);
  int* off_hed   = (int*)alloc((size_t)(H+1)*4);
  int* off_slot  = (int*)alloc((size_t)(NSLOT+1)*4);
  int* mlist     = (int*)alloc((size_t)NB*4);
  int* partials  = (int*)alloc(256);
  ull* rec       = (ull*)alloc((size_t)E*8);
  unsigned* edge_hed = (unsigned*)alloc((size_t)E*4);
  unsigned* edge_src = (unsigned*)alloc((size_t)E*4);
  unsigned short* nm_bf = (unsigned short*)alloc((size_t)NB*64*2);
  unsigned short* he_bf = (unsigned short*)alloc((size_t)H*64*2);
  float* he1    = (float*)alloc((size_t)H*64*4);
  float* naggb  = (float*)alloc((size_t)NB*64*4);
  float* oaggb  = (float*)alloc((size_t)NB*64*4);
  float* inner1 = (float*)alloc((size_t)NB*64*4);

  hipMemsetAsync(zstart, 0, zbytes, stream);

  k_copy4<<<(N*64/4 + 255)/256, 256, 0, stream>>>((const float4*)node_emb, (float4*)out_ne, N*64/4);
  k_set_member<<<(NB+255)/256, 256, 0, stream>>>(node_indices, member, NB);
  k_build_list<<<(N+255)/256, 256, 0, stream>>>(member, mlist, mcount, N);
  k_count_rec<<<(E+255)/256, 256, 0, stream>>>(semalinks, member, rec, cnt_hed, cnt_slot, E);

  int nb_h = (H + 2047)/2048, nb_s = (NSLOT + 2047)/2048;
  k_scan1<<<nb_h, 256, 0, stream>>>(cnt_hed, off_hed, H, partials);
  k_scan2<<<1, 64, 0, stream>>>(partials, nb_h, off_hed, H);
  k_scan3<<<(H+255)/256, 256, 0, stream>>>(off_hed, partials, H);
  k_scan1<<<nb_s, 256, 0, stream>>>(cnt_slot, off_slot, NSLOT, partials);
  k_scan2<<<1, 64, 0, stream>>>(partials, nb_s, off_slot, NSLOT);
  k_scan3<<<(NSLOT+255)/256, 256, 0, stream>>>(off_slot, partials, NSLOT);

  k_scatter_both<<<2048, 256, 0, stream>>>(rec, mcount, off_hed, cur_hed, edge_hed,
                                           off_slot, cur_slot, edge_src, E);

  for (int i = 0; i < L; ++i){
    const float* Wm = W_msg + (size_t)i*4096;
    const float* Wa = W_att + (size_t)i*4096;
    const float* Wu = W_upd + (size_t)i*4096;
    const float* wi1 = Wi1 + (size_t)i*4096;
    const float* wi2 = Wi2 + (size_t)i*4096;
    const float* won = Wo_n + (size_t)i*4096;
    const float* woe = Wo_e + (size_t)i*4096;
    const float* wos = Wo_s + (size_t)i*4096;
    const float* he_cur = (i == 0) ? hyper_emb : he1;
    float* he_next = (i == 0) ? he1 : out_he;

    k_rowmatA<<<800, 256, 0, stream>>>(out_ne, Wm, wi1, mlist, mcount, nm_bf, inner1);
    k_attn_upd<<<1280, 256, 0, stream>>>(off_hed, edge_hed, nm_bf, sema_emb, Wm, Wa, Wu,
                                         he_cur, he_next, he_bf, H);
    k_nodeagg2<<<1280, 256, 0, stream>>>(mcount, off_slot, edge_src, he_bf, sema_emb, naggb, oaggb);
    k_matfuse<<<800, 256, 0, stream>>>(inner1, naggb, oaggb, wi2, won, woe, wos, mlist, mcount, out_ne);
  }
}

// Round 14
// 357.778 us; speedup vs baseline: 1.0452x; 1.0452x over previous
//
#include <hip/hip_runtime.h>
#include <cmath>

// HyperKGL: N=100000, H=20000, NS=10, D=64, L=2, E=1e6, NB=50000
// R13 -> R14: revert the hq-fusion (serial per-wave matvec cost +20us in attn);
// restore R12's k_rowmatB (4x4 blocked GEMM + sema prologue). KEEP the R13
// 4-window grid-2048 scatter (scatter dropped out of top-5: <=30us, was 44.5).

#define EPSF 1e-9f
#define NSLOT 40960
#define SENT 0xFFFFFFFFu
#define ATP 68
typedef unsigned long long ull;

__device__ __forceinline__ float group16_sum(float v){
  v += __shfl_xor(v, 1, 64);
  v += __shfl_xor(v, 2, 64);
  v += __shfl_xor(v, 4, 64);
  v += __shfl_xor(v, 8, 64);
  return v;
}
__device__ __forceinline__ float xgroup_sum(float v){
  v += __shfl_xor(v, 16, 64);
  v += __shfl_xor(v, 32, 64);
  return v;
}
__device__ __forceinline__ unsigned short f2bf(float f){
  unsigned b = __float_as_uint(f);
  unsigned r = (b + 0x7FFFu + ((b >> 16) & 1u)) >> 16;
  return (unsigned short)r;
}
__device__ __forceinline__ float bf2f(unsigned short u){
  return __uint_as_float(((unsigned)u) << 16);
}

// ---------------- setup ----------------
__global__ __launch_bounds__(256) void k_copy4(const float4* __restrict__ in, float4* __restrict__ out, int n){
  int i = blockIdx.x*256 + threadIdx.x;
  if (i < n) out[i] = in[i];
}

__global__ __launch_bounds__(256) void k_set_member(const int* __restrict__ idx, int* __restrict__ member, int n){
  int i = blockIdx.x*256 + threadIdx.x;
  if (i < n) member[idx[i]] = 1;
}

__global__ __launch_bounds__(256) void k_build_list(int* __restrict__ member, int* __restrict__ mlist,
                                                    int* __restrict__ mcount, int N){
  int n = blockIdx.x*256 + threadIdx.x;
  if (n < N && member[n]) {
    int p = atomicAdd(mcount, 1);
    mlist[p] = n;
    member[n] = p + 2;   // slot+2 (0 = non-member)
  }
}

// record build + per-key degree counts in one streaming pass
__global__ __launch_bounds__(256) void k_count_rec(const int* __restrict__ sl, const int* __restrict__ member,
    ull* __restrict__ rec, int* __restrict__ cnt_hed, int* __restrict__ cnt_slot, int E){
  int e = blockIdx.x*256 + threadIdx.x;
  if (e >= E) return;
  int src = sl[3*e];
  int m = member[src];
  if (m){
    int slot = m - 2;
    int hed = sl[3*e+1];
    int sem = sl[3*e+2];
    unsigned lo = (unsigned)slot | ((unsigned)sem << 20);
    rec[e] = (ull)lo | ((ull)(unsigned)hed << 32);
    atomicAdd(&cnt_hed[hed], 1);
    atomicAdd(&cnt_slot[slot], 1);
  } else {
    rec[e] = (ull)SENT << 32;
  }
}

__global__ __launch_bounds__(256) void k_scan1(const int* __restrict__ in, int* __restrict__ out, int n,
                                               int* __restrict__ partials){
  __shared__ int s[256];
  int b = blockIdx.x, t = threadIdx.x;
  int base = b*2048 + t*8;
  int v[8]; int sum = 0;
  #pragma unroll
  for (int j=0;j<8;j++){ int i = base + j; v[j] = (i<n) ? in[i] : 0; sum += v[j]; }
  s[t] = sum;
  __syncthreads();
  for (int o=1;o<256;o<<=1){
    int x = (t>=o) ? s[t-o] : 0;
    __syncthreads();
    s[t] += x;
    __syncthreads();
  }
  int excl = s[t] - sum;
  if (t == 255) partials[b] = s[255];
  int run = excl;
  #pragma unroll
  for (int j=0;j<8;j++){ int i = base + j; if (i<n) out[i] = run; run += v[j]; }
}

__global__ void k_scan2(int* __restrict__ partials, int nb, int* __restrict__ out, int n){
  if (threadIdx.x==0 && blockIdx.x==0){
    int run = 0;
    for (int i=0;i<nb;i++){ int x = partials[i]; partials[i] = run; run += x; }
    out[n] = run;
  }
}

__global__ __launch_bounds__(256) void k_scan3(int* __restrict__ out, const int* __restrict__ partials, int n){
  int i = blockIdx.x*256 + threadIdx.x;
  if (i < n) out[i] += partials[i >> 11];
}

// merged windowed scatter, 4 windows (window = blockIdx&3)
__global__ __launch_bounds__(256) void k_scatter_both(const ull* __restrict__ rec,
    const int* __restrict__ mcountp,
    const int* __restrict__ off_hed, int* __restrict__ cur_hed, unsigned* __restrict__ edge_hed,
    const int* __restrict__ off_slot, int* __restrict__ cur_slot, unsigned* __restrict__ edge_src, int E){
  int w = blockIdx.x & 3;
  int chunk = blockIdx.x >> 2;
  int nchunk = gridDim.x >> 2;
  int per = (E + nchunk - 1) / nchunk;
  int lo_i = chunk * per;
  int hi_i = min(E, lo_i + per);
  int divs = (*mcountp + 3) >> 2;
  for (int i = lo_i + threadIdx.x; i < hi_i; i += 256){
    ull r = rec[i];
    unsigned hed = (unsigned)(r >> 32);
    if (hed == SENT) continue;
    unsigned lo = (unsigned)r;
    int slot = lo & 0xFFFFF;
    if ((int)hed / 5000 == w){
      int p = off_hed[hed] + atomicAdd(&cur_hed[hed], 1);
      edge_hed[p] = lo;
    }
    if (slot / divs == w){
      int p = off_slot[slot] + atomicAdd(&cur_slot[slot], 1);
      edge_src[p] = hed | (lo & 0xFFF00000u);
    }
  }
}

// ================= 4x4 register-blocked GEMM64 =================
#define LOAD_W(Wl, Wsrc) for (int i_=threadIdx.x; i_<1024; i_+=256) ((float4*)Wl)[i_] = ((const float4*)(Wsrc))[i_];

#define STAGE_AT(At, ro, nrows, LOADEXPR)                              \
  {                                                                    \
    int cg_ = threadIdx.x & 15, rl_ = threadIdx.x >> 4;                \
    for (int p_ = 0; p_ < 4; ++p_){                                    \
      int rloc_ = p_*16 + rl_;                                         \
      int r_ = (ro) + rloc_;                                           \
      float4 v_ = make_float4(0.f,0.f,0.f,0.f);                        \
      if (r_ < (nrows)){ v_ = (LOADEXPR); }                            \
      At[cg_*4+0][rloc_] = v_.x;                                       \
      At[cg_*4+1][rloc_] = v_.y;                                       \
      At[cg_*4+2][rloc_] = v_.z;                                       \
      At[cg_*4+3][rloc_] = v_.w;                                       \
    }                                                                  \
  }

__device__ __forceinline__ void gemm44(const float* __restrict__ Wl, const float (*At)[ATP],
                                       int rg4, int cg4, float4 acc[4]){
  #pragma unroll 8
  for (int k = 0; k < 64; ++k){
    const float4 w = *(const float4*)&Wl[k*64 + cg4];
    const float4 a = *(const float4*)&At[k][rg4];
    acc[0].x = fmaf(a.x,w.x,acc[0].x); acc[0].y = fmaf(a.x,w.y,acc[0].y);
    acc[0].z = fmaf(a.x,w.z,acc[0].z); acc[0].w = fmaf(a.x,w.w,acc[0].w);
    acc[1].x = fmaf(a.y,w.x,acc[1].x); acc[1].y = fmaf(a.y,w.y,acc[1].y);
    acc[1].z = fmaf(a.y,w.z,acc[1].z); acc[1].w = fmaf(a.y,w.w,acc[1].w);
    acc[2].x = fmaf(a.z,w.x,acc[2].x); acc[2].y = fmaf(a.z,w.y,acc[2].y);
    acc[2].z = fmaf(a.z,w.z,acc[2].z); acc[2].w = fmaf(a.z,w.w,acc[2].w);
    acc[3].x = fmaf(a.w,w.x,acc[3].x); acc[3].y = fmaf(a.w,w.y,acc[3].y);
    acc[3].z = fmaf(a.w,w.z,acc[3].z); acc[3].w = fmaf(a.w,w.w,acc[3].w);
  }
}

#define ZERO4(a) { a[0]=make_float4(0,0,0,0); a[1]=make_float4(0,0,0,0); a[2]=make_float4(0,0,0,0); a[3]=make_float4(0,0,0,0); }

// rowmatA: nm_bf = bf16(ne[mlist]@Wm) ; inner1 = ne[mlist]@Wi1
__global__ __launch_bounds__(256) void k_rowmatA(const float* __restrict__ ne, const float* __restrict__ Wm,
    const float* __restrict__ Wi1, const int* __restrict__ mlist, const int* __restrict__ mcountp,
    unsigned short* __restrict__ nm_bf, float* __restrict__ inner1){
  __shared__ float W1[4096], W2[4096];
  __shared__ float At[64][ATP];
  int t = threadIdx.x;
  int nrows = *mcountp;
  int ntiles = (nrows + 63) >> 6;
  LOAD_W(W1, Wm)
  LOAD_W(W2, Wi1)
  int cg4 = (t & 15)*4, rg4 = (t >> 4)*4;
  for (int tile = blockIdx.x; tile < ntiles; tile += gridDim.x){
    int ro = tile << 6;
    __syncthreads();
    STAGE_AT(At, ro, nrows, (*(const float4*)&ne[(size_t)mlist[r_]*64 + cg_*4]))
    __syncthreads();
    float4 a1[4]; ZERO4(a1)
    float4 a2[4]; ZERO4(a2)
    #pragma unroll 4
    for (int k = 0; k < 64; ++k){
      const float4 w1 = *(const float4*)&W1[k*64 + cg4];
      const float4 w2 = *(const float4*)&W2[k*64 + cg4];
      const float4 a  = *(const float4*)&At[k][rg4];
      a1[0].x=fmaf(a.x,w1.x,a1[0].x); a1[0].y=fmaf(a.x,w1.y,a1[0].y); a1[0].z=fmaf(a.x,w1.z,a1[0].z); a1[0].w=fmaf(a.x,w1.w,a1[0].w);
      a1[1].x=fmaf(a.y,w1.x,a1[1].x); a1[1].y=fmaf(a.y,w1.y,a1[1].y); a1[1].z=fmaf(a.y,w1.z,a1[1].z); a1[1].w=fmaf(a.y,w1.w,a1[1].w);
      a1[2].x=fmaf(a.z,w1.x,a1[2].x); a1[2].y=fmaf(a.z,w1.y,a1[2].y); a1[2].z=fmaf(a.z,w1.z,a1[2].z); a1[2].w=fmaf(a.z,w1.w,a1[2].w);
      a1[3].x=fmaf(a.w,w1.x,a1[3].x); a1[3].y=fmaf(a.w,w1.y,a1[3].y); a1[3].z=fmaf(a.w,w1.z,a1[3].z); a1[3].w=fmaf(a.w,w1.w,a1[3].w);
      a2[0].x=fmaf(a.x,w2.x,a2[0].x); a2[0].y=fmaf(a.x,w2.y,a2[0].y); a2[0].z=fmaf(a.x,w2.z,a2[0].z); a2[0].w=fmaf(a.x,w2.w,a2[0].w);
      a2[1].x=fmaf(a.y,w2.x,a2[1].x); a2[1].y=fmaf(a.y,w2.y,a2[1].y); a2[1].z=fmaf(a.y,w2.z,a2[1].z); a2[1].w=fmaf(a.y,w2.w,a2[1].w);
      a2[2].x=fmaf(a.z,w2.x,a2[2].x); a2[2].y=fmaf(a.z,w2.y,a2[2].y); a2[2].z=fmaf(a.z,w2.z,a2[2].z); a2[2].w=fmaf(a.z,w2.w,a2[2].w);
      a2[3].x=fmaf(a.w,w2.x,a2[3].x); a2[3].y=fmaf(a.w,w2.y,a2[3].y); a2[3].z=fmaf(a.w,w2.z,a2[3].z); a2[3].w=fmaf(a.w,w2.w,a2[3].w);
    }
    #pragma unroll
    for (int i = 0; i < 4; ++i){
      int r = ro + rg4 + i;
      if (r < nrows){
        ushort4 s;
        s.x = f2bf(a1[i].x); s.y = f2bf(a1[i].y); s.z = f2bf(a1[i].z); s.w = f2bf(a1[i].w);
        *(ushort4*)&nm_bf[(size_t)r*64 + cg4] = s;
        *(float4*)&inner1[(size_t)r*64 + cg4] = a2[i];
      }
    }
  }
}

// rowmatB: hq = he@Wa ; block 0 prologue: smbuf = sema@Wm
__global__ __launch_bounds__(256) void k_rowmatB(const float* __restrict__ he, const float* __restrict__ sema,
    const float* __restrict__ Wa, const float* __restrict__ Wm,
    float* __restrict__ hq, float* __restrict__ smbuf, int H, int NS_){
  __shared__ float W1[4096];
  __shared__ float At[64][ATP];
  int t = threadIdx.x;
  if (blockIdx.x == 0 && t < 160){
    int sr = t >> 4, c4 = (t & 15)*4;
    float4 accs = make_float4(0,0,0,0);
    #pragma unroll 8
    for (int k = 0; k < 64; ++k){
      float a = sema[sr*64 + k];
      float4 w = *(const float4*)&Wm[k*64 + c4];
      accs.x = fmaf(a,w.x,accs.x); accs.y = fmaf(a,w.y,accs.y);
      accs.z = fmaf(a,w.z,accs.z); accs.w = fmaf(a,w.w,accs.w);
    }
    *(float4*)&smbuf[(size_t)sr*64 + c4] = accs;
  }
  LOAD_W(W1, Wa)
  int nrows = H;
  int ntiles = (nrows + 63) >> 6;
  int cg4 = (t & 15)*4, rg4 = (t >> 4)*4;
  for (int tile = blockIdx.x; tile < ntiles; tile += gridDim.x){
    int ro = tile << 6;
    __syncthreads();
    STAGE_AT(At, ro, nrows, (*(const float4*)&he[(size_t)r_*64 + cg_*4]))
    __syncthreads();
    float4 acc[4]; ZERO4(acc)
    gemm44(W1, At, rg4, cg4, acc);
    #pragma unroll
    for (int i = 0; i < 4; ++i){
      int r = ro + rg4 + i;
      if (r < nrows) *(float4*)&hq[(size_t)r*64 + cg4] = acc[i];
    }
  }
}

// matfuse (unchanged)
__global__ __launch_bounds__(256) void k_matfuse(const float* __restrict__ inner1, const float* __restrict__ nagg,
    const float* __restrict__ oagg, const float* __restrict__ Wi2, const float* __restrict__ Wn,
    const float* __restrict__ We, const float* __restrict__ Ws,
    const int* __restrict__ mlist, const int* __restrict__ mcountp, float* __restrict__ ne){
  __shared__ float Wl[4096];
  __shared__ float At[64][ATP];
  int t = threadIdx.x;
  int cnt = *mcountp;
  int ntiles = (cnt + 63) >> 6;
  int cg4 = (t & 15)*4, rg4 = (t >> 4)*4;
  for (int tile = blockIdx.x; tile < ntiles; tile += gridDim.x){
    int ro = tile << 6;
    __syncthreads();
    STAGE_AT(At, ro, cnt, (*(const float4*)&nagg[(size_t)r_*64 + cg_*4]))
    LOAD_W(Wl, Ws)
    __syncthreads();
    float4 acc[4]; ZERO4(acc)
    gemm44(Wl, At, rg4, cg4, acc);   // acc = An@Ws
    __syncthreads();
    LOAD_W(Wl, Wi2)
    __syncthreads();
    float4 p1[4]; ZERO4(p1)
    gemm44(Wl, At, rg4, cg4, p1);    // p1 = An@Wi2
    float x[4][4];
    #pragma unroll
    for (int i = 0; i < 4; ++i){
      int r = ro + rg4 + i;
      float4 v = make_float4(0.f,0.f,0.f,0.f);
      if (r < cnt) v = *(const float4*)&inner1[(size_t)r*64 + cg4];
      float x0 = p1[i].x + v.x, x1 = p1[i].y + v.y, x2 = p1[i].z + v.z, x3 = p1[i].w + v.w;
      x[i][0] = x0 >= 0.f ? x0 : 0.01f*x0;
      x[i][1] = x1 >= 0.f ? x1 : 0.01f*x1;
      x[i][2] = x2 >= 0.f ? x2 : 0.01f*x2;
      x[i][3] = x3 >= 0.f ? x3 : 0.01f*x3;
    }
    __syncthreads();
    #pragma unroll
    for (int i = 0; i < 4; ++i)
      #pragma unroll
      for (int j = 0; j < 4; ++j)
        At[cg4+j][rg4+i] = x[i][j];
    LOAD_W(Wl, Wn)
    __syncthreads();
    gemm44(Wl, At, rg4, cg4, acc);   // acc += Ai@Wn
    __syncthreads();
    STAGE_AT(At, ro, cnt, (*(const float4*)&oagg[(size_t)r_*64 + cg_*4]))
    LOAD_W(Wl, We)
    __syncthreads();
    gemm44(Wl, At, rg4, cg4, acc);   // acc += Ao@We
    #pragma unroll
    for (int i = 0; i < 4; ++i){
      int r = ro + rg4 + i;
      if (r < cnt){
        float4 o = make_float4(tanhf(acc[i].x), tanhf(acc[i].y), tanhf(acc[i].z), tanhf(acc[i].w));
        *(float4*)&ne[(size_t)mlist[r]*64 + cg4] = o;
      }
    }
  }
}

// ---------------- attention + W_upd matvec fused; bf16 nm gathers ----------------
__global__ __launch_bounds__(256) void k_attn_upd(const int* __restrict__ off_hed, const unsigned* __restrict__ edge_hed,
    const unsigned short* __restrict__ nm_bf, const float* __restrict__ smb, const float* __restrict__ hq,
    const float* __restrict__ W, const float* __restrict__ he_cur, float* __restrict__ he_next,
    unsigned short* __restrict__ he_bf, int H){
  __shared__ float Wl[4096];
  __shared__ float sm_lds[640];
  __shared__ float aggl[256];
  int t = threadIdx.x;
  for (int i=t;i<1024;i+=256) ((float4*)Wl)[i] = ((const float4*)W)[i];
  for (int i=t;i<640;i+=256) sm_lds[i] = smb[i];
  __syncthreads();
  int w = t >> 6, lane = t & 63;
  int nhb = (H + 3) >> 2;
  for (int hb = blockIdx.x; hb < nhb; hb += gridDim.x){
    int h = hb*4 + w;
    if (h >= H) continue;
    int start = off_hed[h], end = off_hed[h+1];
    if (start == end){
      float v = he_cur[(size_t)h*64 + lane];
      he_next[(size_t)h*64 + lane] = v;
      he_bf[(size_t)h*64 + lane] = f2bf(v);
      continue;
    }
    int g = lane >> 4, dl = (lane & 15)*4;
    float4 q4 = *(const float4*)&hq[(size_t)h*64 + dl];
    float ax=0.f, ay=0.f, az=0.f, aw=0.f, dsum=0.f, m=-3.4e38f;
    for (int idx0 = start; idx0 < end; idx0 += 4){
      int idx = idx0 + g;
      bool valid = idx < end;
      unsigned u = valid ? edge_hed[idx] : 0u;
      int slot = u & 0xFFFFF, sem = u >> 20;
      float4 nm4 = make_float4(0.f,0.f,0.f,0.f);
      if (valid){
        ushort4 nu = *(const ushort4*)&nm_bf[(size_t)slot*64 + dl];
        nm4 = make_float4(bf2f(nu.x), bf2f(nu.y), bf2f(nu.z), bf2f(nu.w));
      }
      float4 sm4 = *(const float4*)&sm_lds[sem*64 + dl];
      float mkx = nm4.x+sm4.x, mky = nm4.y+sm4.y, mkz = nm4.z+sm4.z, mkw = nm4.w+sm4.w;
      float part = mkx*q4.x + mky*q4.y + mkz*q4.z + mkw*q4.w;
      part = group16_sum(part);
      float l = valid ? part : -3.4e38f;
      float mn = fmaxf(m, l);
      float scale = __expf(m - mn);
      float wgt = valid ? __expf(l - mn) : 0.f;
      ax = ax*scale + wgt*mkx; ay = ay*scale + wgt*mky;
      az = az*scale + wgt*mkz; aw = aw*scale + wgt*mkw;
      dsum = dsum*scale + wgt;
      m = mn;
    }
    float mg = fmaxf(m, __shfl_xor(m, 16, 64));
    mg = fmaxf(mg, __shfl_xor(mg, 32, 64));
    float cs = __expf(m - mg);
    ax*=cs; ay*=cs; az*=cs; aw*=cs; dsum*=cs;
    ax = xgroup_sum(ax); ay = xgroup_sum(ay); az = xgroup_sum(az); aw = xgroup_sum(aw);
    dsum = xgroup_sum(dsum);
    if (lane < 16){
      float inv = 1.f/(dsum + EPSF);
      aggl[w*64 + dl+0] = ax*inv;
      aggl[w*64 + dl+1] = ay*inv;
      aggl[w*64 + dl+2] = az*inv;
      aggl[w*64 + dl+3] = aw*inv;
    }
    float o = 0.f;
    #pragma unroll 8
    for (int j=0;j<64;j++) o = fmaf(aggl[w*64 + j], Wl[j*64 + lane], o);
    float ov = tanhf(o);
    he_next[(size_t)h*64 + lane] = ov;
    he_bf[(size_t)h*64 + lane] = f2bf(ov);
  }
}

// ---------------- per-member-slot aggregation; bf16 he gathers ----------------
__global__ __launch_bounds__(256) void k_nodeagg2(const int* __restrict__ mcountp,
    const int* __restrict__ off_slot, const unsigned* __restrict__ edge_src,
    const unsigned short* __restrict__ he_bf, const float* __restrict__ sema,
    float* __restrict__ nagg, float* __restrict__ oagg){
  __shared__ float sm_lds[640];
  int t = threadIdx.x;
  for (int i=t;i<640;i+=256) sm_lds[i] = sema[i];
  __syncthreads();
  int w = t >> 6, lane = t & 63;
  int mc = *mcountp;
  int npb = (mc + 3) >> 2;
  int g = lane >> 4, dl = (lane & 15)*4;
  for (int pb = blockIdx.x; pb < npb; pb += gridDim.x){
    int p = pb*4 + w;
    if (p >= mc) continue;
    int start = off_slot[p], end = off_slot[p+1];
    float anx=0.f, any_=0.f, anz=0.f, anw=0.f;
    float aox=0.f, aoy=0.f, aoz=0.f, aow=0.f;
    for (int idx0 = start; idx0 < end; idx0 += 4){
      int idx = idx0 + g;
      if (idx < end){
        unsigned u = edge_src[idx];
        int hd = u & 0xFFFFF, sem = u >> 20;
        ushort4 hu = *(const ushort4*)&he_bf[(size_t)hd*64 + dl];
        float4 hv = make_float4(bf2f(hu.x), bf2f(hu.y), bf2f(hu.z), bf2f(hu.w));
        float4 sv = *(const float4*)&sm_lds[sem*64 + dl];
        anx += hv.x; any_ += hv.y; anz += hv.z; anw += hv.w;
        aox = fmaf(hv.x, sv.x, aox); aoy = fmaf(hv.y, sv.y, aoy);
        aoz = fmaf(hv.z, sv.z, aoz); aow = fmaf(hv.w, sv.w, aow);
      }
    }
    anx = xgroup_sum(anx); any_ = xgroup_sum(any_); anz = xgroup_sum(anz); anw = xgroup_sum(anw);
    aox = xgroup_sum(aox); aoy = xgroup_sum(aoy); aoz = xgroup_sum(aoz); aow = xgroup_sum(aow);
    if (lane < 16){
      float inv = 1.f/((float)(end - start) + EPSF);
      *(float4*)&nagg[(size_t)p*64 + dl] = make_float4(anx*inv, any_*inv, anz*inv, anw*inv);
      *(float4*)&oagg[(size_t)p*64 + dl] = make_float4(aox*inv, aoy*inv, aoz*inv, aow*inv);
    }
  }
}

extern "C" void kernel_launch(void* const* d_in, const int* in_sizes, int n_in,
                              void* d_out, int out_size, void* d_ws, size_t ws_size,
                              hipStream_t stream)
{
  (void)in_sizes; (void)n_in; (void)out_size; (void)ws_size;
  const float* node_emb  = (const float*)d_in[0];
  const float* hyper_emb = (const float*)d_in[1];
  const float* sema_emb  = (const float*)d_in[2];
  const float* W_msg = (const float*)d_in[3];
  const float* W_att = (const float*)d_in[4];
  const float* W_upd = (const float*)d_in[5];
  const float* Wi1   = (const float*)d_in[6];
  const float* Wi2   = (const float*)d_in[7];
  const float* Wo_n  = (const float*)d_in[8];
  const float* Wo_e  = (const float*)d_in[9];
  const float* Wo_s  = (const float*)d_in[10];
  const int* node_indices = (const int*)d_in[11];
  const int* semalinks    = (const int*)d_in[14];

  constexpr int N = 100000, H = 20000, NS = 10, L = 2, E = 1000000, NB = 50000;

  float* out_ne = (float*)d_out;                    // N*64
  float* out_he = (float*)d_out + (size_t)N*64;     // H*64

  char* wsp = (char*)d_ws;
  auto alloc = [&](size_t bytes)->char*{ char* p = wsp; wsp += (bytes + 255) & ~(size_t)255; return p; };
  char* zstart = wsp;
  int* member   = (int*)alloc((size_t)N*4);
  int* cnt_hed  = (int*)alloc((size_t)H*4);
  int* cnt_slot = (int*)alloc((size_t)NSLOT*4);
  int* cur_hed  = (int*)alloc((size_t)H*4);
  int* cur_slot = (int*)alloc((size_t)NSLOT*4);
  int* mcount   = (int*)alloc(256);
  size_t zbytes = (size_t)(wsp - zstart);
  int* off_hed   = (int*)alloc((size_t)(H+1)*4);
  int* off_slot  = (int*)alloc((size_t)(NSLOT+1)*4);
  int* mlist     = (int*)alloc((size_t)NB*4);
  int* partials  = (int*)alloc(256);
  ull* rec       = (ull*)alloc((size_t)E*8);
  unsigned* edge_hed = (unsigned*)alloc((size_t)E*4);
  unsigned* edge_src = (unsigned*)alloc((size_t)E*4);
  float* smbuf  = (float*)alloc((size_t)NS*64*4);
  float* hq     = (float*)alloc((size_t)H*64*4);
  unsigned short* nm_bf = (unsigned short*)alloc((size_t)NB*64*2);
  unsigned short* he_bf = (unsigned short*)alloc((size_t)H*64*2);
  float* he1    = (float*)alloc((size_t)H*64*4);
  float* naggb  = (float*)alloc((size_t)NB*64*4);
  float* oaggb  = (float*)alloc((size_t)NB*64*4);
  float* inner1 = (float*)alloc((size_t)NB*64*4);

  hipMemsetAsync(zstart, 0, zbytes, stream);

  k_copy4<<<(N*64/4 + 255)/256, 256, 0, stream>>>((const float4*)node_emb, (float4*)out_ne, N*64/4);
  k_set_member<<<(NB+255)/256, 256, 0, stream>>>(node_indices, member, NB);
  k_build_list<<<(N+255)/256, 256, 0, stream>>>(member, mlist, mcount, N);
  k_count_rec<<<(E+255)/256, 256, 0, stream>>>(semalinks, member, rec, cnt_hed, cnt_slot, E);

  int nb_h = (H + 2047)/2048, nb_s = (NSLOT + 2047)/2048;
  k_scan1<<<nb_h, 256, 0, stream>>>(cnt_hed, off_hed, H, partials);
  k_scan2<<<1, 64, 0, stream>>>(partials, nb_h, off_hed, H);
  k_scan3<<<(H+255)/256, 256, 0, stream>>>(off_hed, partials, H);
  k_scan1<<<nb_s, 256, 0, stream>>>(cnt_slot, off_slot, NSLOT, partials);
  k_scan2<<<1, 64, 0, stream>>>(partials, nb_s, off_slot, NSLOT);
  k_scan3<<<(NSLOT+255)/256, 256, 0, stream>>>(off_slot, partials, NSLOT);

  k_scatter_both<<<2048, 256, 0, stream>>>(rec, mcount, off_hed, cur_hed, edge_hed,
                                           off_slot, cur_slot, edge_src, E);

  for (int i = 0; i < L; ++i){
    const float* Wm = W_msg + (size_t)i*4096;
    const float* Wa = W_att + (size_t)i*4096;
    const float* Wu = W_upd + (size_t)i*4096;
    const float* wi1 = Wi1 + (size_t)i*4096;
    const float* wi2 = Wi2 + (size_t)i*4096;
    const float* won = Wo_n + (size_t)i*4096;
    const float* woe = Wo_e + (size_t)i*4096;
    const float* wos = Wo_s + (size_t)i*4096;
    const float* he_cur = (i == 0) ? hyper_emb : he1;
    float* he_next = (i == 0) ? he1 : out_he;

    k_rowmatA<<<800, 256, 0, stream>>>(out_ne, Wm, wi1, mlist, mcount, nm_bf, inner1);
    k_rowmatB<<<320, 256, 0, stream>>>(he_cur, sema_emb, Wa, Wm, hq, smbuf, H, NS);
    k_attn_upd<<<1280, 256, 0, stream>>>(off_hed, edge_hed, nm_bf, smbuf, hq, Wu,
                                         he_cur, he_next, he_bf, H);
    k_nodeagg2<<<1280, 256, 0, stream>>>(mcount, off_slot, edge_src, he_bf, sema_emb, naggb, oaggb);
    k_matfuse<<<800, 256, 0, stream>>>(inner1, naggb, oaggb, wi2, won, woe, wos, mlist, mcount, out_ne);
  }
}

// Round 15
// 309.778 us; speedup vs baseline: 1.2072x; 1.1550x over previous
//
#include <hip/hip_runtime.h>
#include <cmath>

// HyperKGL: N=100000, H=20000, NS=10, D=64, L=2, E=1e6, NB=50000
// R14 -> R15: rank-based atomic-free scatter. k_count_rec's atomicAdd return
// value IS the edge's CSR rank -> store as ushort2; k_scatter_both becomes pure
// streaming (p = off[key] + rank), no cursor atomics/arrays. attn/nodeagg grid
// 1280 -> 2048 (occupancy 42% -> ~full; gather-latency hiding).

#define EPSF 1e-9f
#define NSLOT 40960
#define SENT 0xFFFFFFFFu
#define ATP 68
typedef unsigned long long ull;

__device__ __forceinline__ float group16_sum(float v){
  v += __shfl_xor(v, 1, 64);
  v += __shfl_xor(v, 2, 64);
  v += __shfl_xor(v, 4, 64);
  v += __shfl_xor(v, 8, 64);
  return v;
}
__device__ __forceinline__ float xgroup_sum(float v){
  v += __shfl_xor(v, 16, 64);
  v += __shfl_xor(v, 32, 64);
  return v;
}
__device__ __forceinline__ unsigned short f2bf(float f){
  unsigned b = __float_as_uint(f);
  unsigned r = (b + 0x7FFFu + ((b >> 16) & 1u)) >> 16;
  return (unsigned short)r;
}
__device__ __forceinline__ float bf2f(unsigned short u){
  return __uint_as_float(((unsigned)u) << 16);
}

// ---------------- setup ----------------
__global__ __launch_bounds__(256) void k_copy4(const float4* __restrict__ in, float4* __restrict__ out, int n){
  int i = blockIdx.x*256 + threadIdx.x;
  if (i < n) out[i] = in[i];
}

__global__ __launch_bounds__(256) void k_set_member(const int* __restrict__ idx, int* __restrict__ member, int n){
  int i = blockIdx.x*256 + threadIdx.x;
  if (i < n) member[idx[i]] = 1;
}

__global__ __launch_bounds__(256) void k_build_list(int* __restrict__ member, int* __restrict__ mlist,
                                                    int* __restrict__ mcount, int N){
  int n = blockIdx.x*256 + threadIdx.x;
  if (n < N && member[n]) {
    int p = atomicAdd(mcount, 1);
    mlist[p] = n;
    member[n] = p + 2;   // slot+2 (0 = non-member)
  }
}

// record build + degree counts + CSR ranks (atomicAdd return) in one pass
__global__ __launch_bounds__(256) void k_count_rec(const int* __restrict__ sl, const int* __restrict__ member,
    ull* __restrict__ rec, ushort2* __restrict__ ranks,
    int* __restrict__ cnt_hed, int* __restrict__ cnt_slot, int E){
  int e = blockIdx.x*256 + threadIdx.x;
  if (e >= E) return;
  int src = sl[3*e];
  int m = member[src];
  if (m){
    int slot = m - 2;
    int hed = sl[3*e+1];
    int sem = sl[3*e+2];
    unsigned lo = (unsigned)slot | ((unsigned)sem << 20);
    rec[e] = (ull)lo | ((ull)(unsigned)hed << 32);
    int r1 = atomicAdd(&cnt_hed[hed], 1);
    int r2 = atomicAdd(&cnt_slot[slot], 1);
    ushort2 rk; rk.x = (unsigned short)r1; rk.y = (unsigned short)r2;
    ranks[e] = rk;
  } else {
    rec[e] = (ull)SENT << 32;
  }
}

__global__ __launch_bounds__(256) void k_scan1(const int* __restrict__ in, int* __restrict__ out, int n,
                                               int* __restrict__ partials){
  __shared__ int s[256];
  int b = blockIdx.x, t = threadIdx.x;
  int base = b*2048 + t*8;
  int v[8]; int sum = 0;
  #pragma unroll
  for (int j=0;j<8;j++){ int i = base + j; v[j] = (i<n) ? in[i] : 0; sum += v[j]; }
  s[t] = sum;
  __syncthreads();
  for (int o=1;o<256;o<<=1){
    int x = (t>=o) ? s[t-o] : 0;
    __syncthreads();
    s[t] += x;
    __syncthreads();
  }
  int excl = s[t] - sum;
  if (t == 255) partials[b] = s[255];
  int run = excl;
  #pragma unroll
  for (int j=0;j<8;j++){ int i = base + j; if (i<n) out[i] = run; run += v[j]; }
}

__global__ void k_scan2(int* __restrict__ partials, int nb, int* __restrict__ out, int n){
  if (threadIdx.x==0 && blockIdx.x==0){
    int run = 0;
    for (int i=0;i<nb;i++){ int x = partials[i]; partials[i] = run; run += x; }
    out[n] = run;
  }
}

__global__ __launch_bounds__(256) void k_scan3(int* __restrict__ out, const int* __restrict__ partials, int n){
  int i = blockIdx.x*256 + threadIdx.x;
  if (i < n) out[i] += partials[i >> 11];
}

// atomic-free windowed scatter: p = off[key] + rank (4 windows for write locality)
__global__ __launch_bounds__(256) void k_scatter_both(const ull* __restrict__ rec,
    const ushort2* __restrict__ ranks, const int* __restrict__ mcountp,
    const int* __restrict__ off_hed, unsigned* __restrict__ edge_hed,
    const int* __restrict__ off_slot, unsigned* __restrict__ edge_src, int E){
  int w = blockIdx.x & 3;
  int chunk = blockIdx.x >> 2;
  int nchunk = gridDim.x >> 2;
  int per = (E + nchunk - 1) / nchunk;
  int lo_i = chunk * per;
  int hi_i = min(E, lo_i + per);
  int divs = (*mcountp + 3) >> 2;
  for (int i = lo_i + threadIdx.x; i < hi_i; i += 256){
    ull r = rec[i];
    unsigned hed = (unsigned)(r >> 32);
    if (hed == SENT) continue;
    unsigned lo = (unsigned)r;
    int slot = lo & 0xFFFFF;
    ushort2 rk = ranks[i];
    if ((int)hed / 5000 == w){
      edge_hed[off_hed[hed] + rk.x] = lo;
    }
    if (slot / divs == w){
      edge_src[off_slot[slot] + rk.y] = hed | (lo & 0xFFF00000u);
    }
  }
}

// ================= 4x4 register-blocked GEMM64 =================
#define LOAD_W(Wl, Wsrc) for (int i_=threadIdx.x; i_<1024; i_+=256) ((float4*)Wl)[i_] = ((const float4*)(Wsrc))[i_];

#define STAGE_AT(At, ro, nrows, LOADEXPR)                              \
  {                                                                    \
    int cg_ = threadIdx.x & 15, rl_ = threadIdx.x >> 4;                \
    for (int p_ = 0; p_ < 4; ++p_){                                    \
      int rloc_ = p_*16 + rl_;                                         \
      int r_ = (ro) + rloc_;                                           \
      float4 v_ = make_float4(0.f,0.f,0.f,0.f);                        \
      if (r_ < (nrows)){ v_ = (LOADEXPR); }                            \
      At[cg_*4+0][rloc_] = v_.x;                                       \
      At[cg_*4+1][rloc_] = v_.y;                                       \
      At[cg_*4+2][rloc_] = v_.z;                                       \
      At[cg_*4+3][rloc_] = v_.w;                                       \
    }                                                                  \
  }

__device__ __forceinline__ void gemm44(const float* __restrict__ Wl, const float (*At)[ATP],
                                       int rg4, int cg4, float4 acc[4]){
  #pragma unroll 8
  for (int k = 0; k < 64; ++k){
    const float4 w = *(const float4*)&Wl[k*64 + cg4];
    const float4 a = *(const float4*)&At[k][rg4];
    acc[0].x = fmaf(a.x,w.x,acc[0].x); acc[0].y = fmaf(a.x,w.y,acc[0].y);
    acc[0].z = fmaf(a.x,w.z,acc[0].z); acc[0].w = fmaf(a.x,w.w,acc[0].w);
    acc[1].x = fmaf(a.y,w.x,acc[1].x); acc[1].y = fmaf(a.y,w.y,acc[1].y);
    acc[1].z = fmaf(a.y,w.z,acc[1].z); acc[1].w = fmaf(a.y,w.w,acc[1].w);
    acc[2].x = fmaf(a.z,w.x,acc[2].x); acc[2].y = fmaf(a.z,w.y,acc[2].y);
    acc[2].z = fmaf(a.z,w.z,acc[2].z); acc[2].w = fmaf(a.z,w.w,acc[2].w);
    acc[3].x = fmaf(a.w,w.x,acc[3].x); acc[3].y = fmaf(a.w,w.y,acc[3].y);
    acc[3].z = fmaf(a.w,w.z,acc[3].z); acc[3].w = fmaf(a.w,w.w,acc[3].w);
  }
}

#define ZERO4(a) { a[0]=make_float4(0,0,0,0); a[1]=make_float4(0,0,0,0); a[2]=make_float4(0,0,0,0); a[3]=make_float4(0,0,0,0); }

// rowmatA: nm_bf = bf16(ne[mlist]@Wm) ; inner1 = ne[mlist]@Wi1
__global__ __launch_bounds__(256) void k_rowmatA(const float* __restrict__ ne, const float* __restrict__ Wm,
    const float* __restrict__ Wi1, const int* __restrict__ mlist, const int* __restrict__ mcountp,
    unsigned short* __restrict__ nm_bf, float* __restrict__ inner1){
  __shared__ float W1[4096], W2[4096];
  __shared__ float At[64][ATP];
  int t = threadIdx.x;
  int nrows = *mcountp;
  int ntiles = (nrows + 63) >> 6;
  LOAD_W(W1, Wm)
  LOAD_W(W2, Wi1)
  int cg4 = (t & 15)*4, rg4 = (t >> 4)*4;
  for (int tile = blockIdx.x; tile < ntiles; tile += gridDim.x){
    int ro = tile << 6;
    __syncthreads();
    STAGE_AT(At, ro, nrows, (*(const float4*)&ne[(size_t)mlist[r_]*64 + cg_*4]))
    __syncthreads();
    float4 a1[4]; ZERO4(a1)
    float4 a2[4]; ZERO4(a2)
    #pragma unroll 4
    for (int k = 0; k < 64; ++k){
      const float4 w1 = *(const float4*)&W1[k*64 + cg4];
      const float4 w2 = *(const float4*)&W2[k*64 + cg4];
      const float4 a  = *(const float4*)&At[k][rg4];
      a1[0].x=fmaf(a.x,w1.x,a1[0].x); a1[0].y=fmaf(a.x,w1.y,a1[0].y); a1[0].z=fmaf(a.x,w1.z,a1[0].z); a1[0].w=fmaf(a.x,w1.w,a1[0].w);
      a1[1].x=fmaf(a.y,w1.x,a1[1].x); a1[1].y=fmaf(a.y,w1.y,a1[1].y); a1[1].z=fmaf(a.y,w1.z,a1[1].z); a1[1].w=fmaf(a.y,w1.w,a1[1].w);
      a1[2].x=fmaf(a.z,w1.x,a1[2].x); a1[2].y=fmaf(a.z,w1.y,a1[2].y); a1[2].z=fmaf(a.z,w1.z,a1[2].z); a1[2].w=fmaf(a.z,w1.w,a1[2].w);
      a1[3].x=fmaf(a.w,w1.x,a1[3].x); a1[3].y=fmaf(a.w,w1.y,a1[3].y); a1[3].z=fmaf(a.w,w1.z,a1[3].z); a1[3].w=fmaf(a.w,w1.w,a1[3].w);
      a2[0].x=fmaf(a.x,w2.x,a2[0].x); a2[0].y=fmaf(a.x,w2.y,a2[0].y); a2[0].z=fmaf(a.x,w2.z,a2[0].z); a2[0].w=fmaf(a.x,w2.w,a2[0].w);
      a2[1].x=fmaf(a.y,w2.x,a2[1].x); a2[1].y=fmaf(a.y,w2.y,a2[1].y); a2[1].z=fmaf(a.y,w2.z,a2[1].z); a2[1].w=fmaf(a.y,w2.w,a2[1].w);
      a2[2].x=fmaf(a.z,w2.x,a2[2].x); a2[2].y=fmaf(a.z,w2.y,a2[2].y); a2[2].z=fmaf(a.z,w2.z,a2[2].z); a2[2].w=fmaf(a.z,w2.w,a2[2].w);
      a2[3].x=fmaf(a.w,w2.x,a2[3].x); a2[3].y=fmaf(a.w,w2.y,a2[3].y); a2[3].z=fmaf(a.w,w2.z,a2[3].z); a2[3].w=fmaf(a.w,w2.w,a2[3].w);
    }
    #pragma unroll
    for (int i = 0; i < 4; ++i){
      int r = ro + rg4 + i;
      if (r < nrows){
        ushort4 s;
        s.x = f2bf(a1[i].x); s.y = f2bf(a1[i].y); s.z = f2bf(a1[i].z); s.w = f2bf(a1[i].w);
        *(ushort4*)&nm_bf[(size_t)r*64 + cg4] = s;
        *(float4*)&inner1[(size_t)r*64 + cg4] = a2[i];
      }
    }
  }
}

// rowmatB: hq = he@Wa ; block 0 prologue: smbuf = sema@Wm
__global__ __launch_bounds__(256) void k_rowmatB(const float* __restrict__ he, const float* __restrict__ sema,
    const float* __restrict__ Wa, const float* __restrict__ Wm,
    float* __restrict__ hq, float* __restrict__ smbuf, int H, int NS_){
  __shared__ float W1[4096];
  __shared__ float At[64][ATP];
  int t = threadIdx.x;
  if (blockIdx.x == 0 && t < 160){
    int sr = t >> 4, c4 = (t & 15)*4;
    float4 accs = make_float4(0,0,0,0);
    #pragma unroll 8
    for (int k = 0; k < 64; ++k){
      float a = sema[sr*64 + k];
      float4 w = *(const float4*)&Wm[k*64 + c4];
      accs.x = fmaf(a,w.x,accs.x); accs.y = fmaf(a,w.y,accs.y);
      accs.z = fmaf(a,w.z,accs.z); accs.w = fmaf(a,w.w,accs.w);
    }
    *(float4*)&smbuf[(size_t)sr*64 + c4] = accs;
  }
  LOAD_W(W1, Wa)
  int nrows = H;
  int ntiles = (nrows + 63) >> 6;
  int cg4 = (t & 15)*4, rg4 = (t >> 4)*4;
  for (int tile = blockIdx.x; tile < ntiles; tile += gridDim.x){
    int ro = tile << 6;
    __syncthreads();
    STAGE_AT(At, ro, nrows, (*(const float4*)&he[(size_t)r_*64 + cg_*4]))
    __syncthreads();
    float4 acc[4]; ZERO4(acc)
    gemm44(W1, At, rg4, cg4, acc);
    #pragma unroll
    for (int i = 0; i < 4; ++i){
      int r = ro + rg4 + i;
      if (r < nrows) *(float4*)&hq[(size_t)r*64 + cg4] = acc[i];
    }
  }
}

// matfuse (unchanged)
__global__ __launch_bounds__(256) void k_matfuse(const float* __restrict__ inner1, const float* __restrict__ nagg,
    const float* __restrict__ oagg, const float* __restrict__ Wi2, const float* __restrict__ Wn,
    const float* __restrict__ We, const float* __restrict__ Ws,
    const int* __restrict__ mlist, const int* __restrict__ mcountp, float* __restrict__ ne){
  __shared__ float Wl[4096];
  __shared__ float At[64][ATP];
  int t = threadIdx.x;
  int cnt = *mcountp;
  int ntiles = (cnt + 63) >> 6;
  int cg4 = (t & 15)*4, rg4 = (t >> 4)*4;
  for (int tile = blockIdx.x; tile < ntiles; tile += gridDim.x){
    int ro = tile << 6;
    __syncthreads();
    STAGE_AT(At, ro, cnt, (*(const float4*)&nagg[(size_t)r_*64 + cg_*4]))
    LOAD_W(Wl, Ws)
    __syncthreads();
    float4 acc[4]; ZERO4(acc)
    gemm44(Wl, At, rg4, cg4, acc);   // acc = An@Ws
    __syncthreads();
    LOAD_W(Wl, Wi2)
    __syncthreads();
    float4 p1[4]; ZERO4(p1)
    gemm44(Wl, At, rg4, cg4, p1);    // p1 = An@Wi2
    float x[4][4];
    #pragma unroll
    for (int i = 0; i < 4; ++i){
      int r = ro + rg4 + i;
      float4 v = make_float4(0.f,0.f,0.f,0.f);
      if (r < cnt) v = *(const float4*)&inner1[(size_t)r*64 + cg4];
      float x0 = p1[i].x + v.x, x1 = p1[i].y + v.y, x2 = p1[i].z + v.z, x3 = p1[i].w + v.w;
      x[i][0] = x0 >= 0.f ? x0 : 0.01f*x0;
      x[i][1] = x1 >= 0.f ? x1 : 0.01f*x1;
      x[i][2] = x2 >= 0.f ? x2 : 0.01f*x2;
      x[i][3] = x3 >= 0.f ? x3 : 0.01f*x3;
    }
    __syncthreads();
    #pragma unroll
    for (int i = 0; i < 4; ++i)
      #pragma unroll
      for (int j = 0; j < 4; ++j)
        At[cg4+j][rg4+i] = x[i][j];
    LOAD_W(Wl, Wn)
    __syncthreads();
    gemm44(Wl, At, rg4, cg4, acc);   // acc += Ai@Wn
    __syncthreads();
    STAGE_AT(At, ro, cnt, (*(const float4*)&oagg[(size_t)r_*64 + cg_*4]))
    LOAD_W(Wl, We)
    __syncthreads();
    gemm44(Wl, At, rg4, cg4, acc);   // acc += Ao@We
    #pragma unroll
    for (int i = 0; i < 4; ++i){
      int r = ro + rg4 + i;
      if (r < cnt){
        float4 o = make_float4(tanhf(acc[i].x), tanhf(acc[i].y), tanhf(acc[i].z), tanhf(acc[i].w));
        *(float4*)&ne[(size_t)mlist[r]*64 + cg4] = o;
      }
    }
  }
}

// ---------------- attention + W_upd matvec fused; bf16 nm gathers ----------------
__global__ __launch_bounds__(256) void k_attn_upd(const int* __restrict__ off_hed, const unsigned* __restrict__ edge_hed,
    const unsigned short* __restrict__ nm_bf, const float* __restrict__ smb, const float* __restrict__ hq,
    const float* __restrict__ W, const float* __restrict__ he_cur, float* __restrict__ he_next,
    unsigned short* __restrict__ he_bf, int H){
  __shared__ float Wl[4096];
  __shared__ float sm_lds[640];
  __shared__ float aggl[256];
  int t = threadIdx.x;
  for (int i=t;i<1024;i+=256) ((float4*)Wl)[i] = ((const float4*)W)[i];
  for (int i=t;i<640;i+=256) sm_lds[i] = smb[i];
  __syncthreads();
  int w = t >> 6, lane = t & 63;
  int nhb = (H + 3) >> 2;
  for (int hb = blockIdx.x; hb < nhb; hb += gridDim.x){
    int h = hb*4 + w;
    if (h >= H) continue;
    int start = off_hed[h], end = off_hed[h+1];
    if (start == end){
      float v = he_cur[(size_t)h*64 + lane];
      he_next[(size_t)h*64 + lane] = v;
      he_bf[(size_t)h*64 + lane] = f2bf(v);
      continue;
    }
    int g = lane >> 4, dl = (lane & 15)*4;
    float4 q4 = *(const float4*)&hq[(size_t)h*64 + dl];
    float ax=0.f, ay=0.f, az=0.f, aw=0.f, dsum=0.f, m=-3.4e38f;
    for (int idx0 = start; idx0 < end; idx0 += 4){
      int idx = idx0 + g;
      bool valid = idx < end;
      unsigned u = valid ? edge_hed[idx] : 0u;
      int slot = u & 0xFFFFF, sem = u >> 20;
      float4 nm4 = make_float4(0.f,0.f,0.f,0.f);
      if (valid){
        ushort4 nu = *(const ushort4*)&nm_bf[(size_t)slot*64 + dl];
        nm4 = make_float4(bf2f(nu.x), bf2f(nu.y), bf2f(nu.z), bf2f(nu.w));
      }
      float4 sm4 = *(const float4*)&sm_lds[sem*64 + dl];
      float mkx = nm4.x+sm4.x, mky = nm4.y+sm4.y, mkz = nm4.z+sm4.z, mkw = nm4.w+sm4.w;
      float part = mkx*q4.x + mky*q4.y + mkz*q4.z + mkw*q4.w;
      part = group16_sum(part);
      float l = valid ? part : -3.4e38f;
      float mn = fmaxf(m, l);
      float scale = __expf(m - mn);
      float wgt = valid ? __expf(l - mn) : 0.f;
      ax = ax*scale + wgt*mkx; ay = ay*scale + wgt*mky;
      az = az*scale + wgt*mkz; aw = aw*scale + wgt*mkw;
      dsum = dsum*scale + wgt;
      m = mn;
    }
    float mg = fmaxf(m, __shfl_xor(m, 16, 64));
    mg = fmaxf(mg, __shfl_xor(mg, 32, 64));
    float cs = __expf(m - mg);
    ax*=cs; ay*=cs; az*=cs; aw*=cs; dsum*=cs;
    ax = xgroup_sum(ax); ay = xgroup_sum(ay); az = xgroup_sum(az); aw = xgroup_sum(aw);
    dsum = xgroup_sum(dsum);
    if (lane < 16){
      float inv = 1.f/(dsum + EPSF);
      aggl[w*64 + dl+0] = ax*inv;
      aggl[w*64 + dl+1] = ay*inv;
      aggl[w*64 + dl+2] = az*inv;
      aggl[w*64 + dl+3] = aw*inv;
    }
    float o = 0.f;
    #pragma unroll 8
    for (int j=0;j<64;j++) o = fmaf(aggl[w*64 + j], Wl[j*64 + lane], o);
    float ov = tanhf(o);
    he_next[(size_t)h*64 + lane] = ov;
    he_bf[(size_t)h*64 + lane] = f2bf(ov);
  }
}

// ---------------- per-member-slot aggregation; bf16 he gathers ----------------
__global__ __launch_bounds__(256) void k_nodeagg2(const int* __restrict__ mcountp,
    const int* __restrict__ off_slot, const unsigned* __restrict__ edge_src,
    const unsigned short* __restrict__ he_bf, const float* __restrict__ sema,
    float* __restrict__ nagg, float* __restrict__ oagg){
  __shared__ float sm_lds[640];
  int t = threadIdx.x;
  for (int i=t;i<640;i+=256) sm_lds[i] = sema[i];
  __syncthreads();
  int w = t >> 6, lane = t & 63;
  int mc = *mcountp;
  int npb = (mc + 3) >> 2;
  int g = lane >> 4, dl = (lane & 15)*4;
  for (int pb = blockIdx.x; pb < npb; pb += gridDim.x){
    int p = pb*4 + w;
    if (p >= mc) continue;
    int start = off_slot[p], end = off_slot[p+1];
    float anx=0.f, any_=0.f, anz=0.f, anw=0.f;
    float aox=0.f, aoy=0.f, aoz=0.f, aow=0.f;
    for (int idx0 = start; idx0 < end; idx0 += 4){
      int idx = idx0 + g;
      if (idx < end){
        unsigned u = edge_src[idx];
        int hd = u & 0xFFFFF, sem = u >> 20;
        ushort4 hu = *(const ushort4*)&he_bf[(size_t)hd*64 + dl];
        float4 hv = make_float4(bf2f(hu.x), bf2f(hu.y), bf2f(hu.z), bf2f(hu.w));
        float4 sv = *(const float4*)&sm_lds[sem*64 + dl];
        anx += hv.x; any_ += hv.y; anz += hv.z; anw += hv.w;
        aox = fmaf(hv.x, sv.x, aox); aoy = fmaf(hv.y, sv.y, aoy);
        aoz = fmaf(hv.z, sv.z, aoz); aow = fmaf(hv.w, sv.w, aow);
      }
    }
    anx = xgroup_sum(anx); any_ = xgroup_sum(any_); anz = xgroup_sum(anz); anw = xgroup_sum(anw);
    aox = xgroup_sum(aox); aoy = xgroup_sum(aoy); aoz = xgroup_sum(aoz); aow = xgroup_sum(aow);
    if (lane < 16){
      float inv = 1.f/((float)(end - start) + EPSF);
      *(float4*)&nagg[(size_t)p*64 + dl] = make_float4(anx*inv, any_*inv, anz*inv, anw*inv);
      *(float4*)&oagg[(size_t)p*64 + dl] = make_float4(aox*inv, aoy*inv, aoz*inv, aow*inv);
    }
  }
}

extern "C" void kernel_launch(void* const* d_in, const int* in_sizes, int n_in,
                              void* d_out, int out_size, void* d_ws, size_t ws_size,
                              hipStream_t stream)
{
  (void)in_sizes; (void)n_in; (void)out_size; (void)ws_size;
  const float* node_emb  = (const float*)d_in[0];
  const float* hyper_emb = (const float*)d_in[1];
  const float* sema_emb  = (const float*)d_in[2];
  const float* W_msg = (const float*)d_in[3];
  const float* W_att = (const float*)d_in[4];
  const float* W_upd = (const float*)d_in[5];
  const float* Wi1   = (const float*)d_in[6];
  const float* Wi2   = (const float*)d_in[7];
  const float* Wo_n  = (const float*)d_in[8];
  const float* Wo_e  = (const float*)d_in[9];
  const float* Wo_s  = (const float*)d_in[10];
  const int* node_indices = (const int*)d_in[11];
  const int* semalinks    = (const int*)d_in[14];

  constexpr int N = 100000, H = 20000, NS = 10, L = 2, E = 1000000, NB = 50000;

  float* out_ne = (float*)d_out;                    // N*64
  float* out_he = (float*)d_out + (size_t)N*64;     // H*64

  char* wsp = (char*)d_ws;
  auto alloc = [&](size_t bytes)->char*{ char* p = wsp; wsp += (bytes + 255) & ~(size_t)255; return p; };
  char* zstart = wsp;
  int* member   = (int*)alloc((size_t)N*4);
  int* cnt_hed  = (int*)alloc((size_t)H*4);
  int* cnt_slot = (int*)alloc((size_t)NSLOT*4);
  int* mcount   = (int*)alloc(256);
  size_t zbytes = (size_t)(wsp - zstart);
  int* off_hed   = (int*)alloc((size_t)(H+1)*4);
  int* off_slot  = (int*)alloc((size_t)(NSLOT+1)*4);
  int* mlist     = (int*)alloc((size_t)NB*4);
  int* partials  = (int*)alloc(256);
  ull* rec       = (ull*)alloc((size_t)E*8);
  ushort2* ranks = (ushort2*)alloc((size_t)E*4);
  unsigned* edge_hed = (unsigned*)alloc((size_t)E*4);
  unsigned* edge_src = (unsigned*)alloc((size_t)E*4);
  float* smbuf  = (float*)alloc((size_t)NS*64*4);
  float* hq     = (float*)alloc((size_t)H*64*4);
  unsigned short* nm_bf = (unsigned short*)alloc((size_t)NB*64*2);
  unsigned short* he_bf = (unsigned short*)alloc((size_t)H*64*2);
  float* he1    = (float*)alloc((size_t)H*64*4);
  float* naggb  = (float*)alloc((size_t)NB*64*4);
  float* oaggb  = (float*)alloc((size_t)NB*64*4);
  float* inner1 = (float*)alloc((size_t)NB*64*4);

  hipMemsetAsync(zstart, 0, zbytes, stream);

  k_copy4<<<(N*64/4 + 255)/256, 256, 0, stream>>>((const float4*)node_emb, (float4*)out_ne, N*64/4);
  k_set_member<<<(NB+255)/256, 256, 0, stream>>>(node_indices, member, NB);
  k_build_list<<<(N+255)/256, 256, 0, stream>>>(member, mlist, mcount, N);
  k_count_rec<<<(E+255)/256, 256, 0, stream>>>(semalinks, member, rec, ranks, cnt_hed, cnt_slot, E);

  int nb_h = (H + 2047)/2048, nb_s = (NSLOT + 2047)/2048;
  k_scan1<<<nb_h, 256, 0, stream>>>(cnt_hed, off_hed, H, partials);
  k_scan2<<<1, 64, 0, stream>>>(partials, nb_h, off_hed, H);
  k_scan3<<<(H+255)/256, 256, 0, stream>>>(off_hed, partials, H);
  k_scan1<<<nb_s, 256, 0, stream>>>(cnt_slot, off_slot, NSLOT, partials);
  k_scan2<<<1, 64, 0, stream>>>(partials, nb_s, off_slot, NSLOT);
  k_scan3<<<(NSLOT+255)/256, 256, 0, stream>>>(off_slot, partials, NSLOT);

  k_scatter_both<<<2048, 256, 0, stream>>>(rec, ranks, mcount, off_hed, edge_hed,
                                           off_slot, edge_src, E);

  for (int i = 0; i < L; ++i){
    const float* Wm = W_msg + (size_t)i*4096;
    const float* Wa = W_att + (size_t)i*4096;
    const float* Wu = W_upd + (size_t)i*4096;
    const float* wi1 = Wi1 + (size_t)i*4096;
    const float* wi2 = Wi2 + (size_t)i*4096;
    const float* won = Wo_n + (size_t)i*4096;
    const float* woe = Wo_e + (size_t)i*4096;
    const float* wos = Wo_s + (size_t)i*4096;
    const float* he_cur = (i == 0) ? hyper_emb : he1;
    float* he_next = (i == 0) ? he1 : out_he;

    k_rowmatA<<<800, 256, 0, stream>>>(out_ne, Wm, wi1, mlist, mcount, nm_bf, inner1);
    k_rowmatB<<<320, 256, 0, stream>>>(he_cur, sema_emb, Wa, Wm, hq, smbuf, H, NS);
    k_attn_upd<<<2048, 256, 0, stream>>>(off_hed, edge_hed, nm_bf, smbuf, hq, Wu,
                                         he_cur, he_next, he_bf, H);
    k_nodeagg2<<<2048, 256, 0, stream>>>(mcount, off_slot, edge_src, he_bf, sema_emb, naggb, oaggb);
    k_matfuse<<<800, 256, 0, stream>>>(inner1, naggb, oaggb, wi2, won, woe, wos, mlist, mcount, out_ne);
  }
}

// Round 16
// 302.789 us; speedup vs baseline: 1.2351x; 1.0231x over previous
//
#include <hip/hip_runtime.h>
#include <cmath>

// HyperKGL: N=100000, H=20000, NS=10, D=64, L=2, E=1e6, NB=50000
// R15 -> R16: k_count_rec atomic-latency fix: (1) counters padded to one per
// 64B line (stride 16) -> same-line atomic contention ~600 -> ~39, kills
// cross-XCD line-migration serialization; (2) the independent ne:=node_emb
// copy fused into count_rec as grid-stride tail (fills idle cycles during
// atomic waits; deletes k_copy4 launch). Scans read stride-16 counters.

#define EPSF 1e-9f
#define NSLOT 40960
#define SENT 0xFFFFFFFFu
#define ATP 68
#define CPAD 16
typedef unsigned long long ull;

__device__ __forceinline__ float group16_sum(float v){
  v += __shfl_xor(v, 1, 64);
  v += __shfl_xor(v, 2, 64);
  v += __shfl_xor(v, 4, 64);
  v += __shfl_xor(v, 8, 64);
  return v;
}
__device__ __forceinline__ float xgroup_sum(float v){
  v += __shfl_xor(v, 16, 64);
  v += __shfl_xor(v, 32, 64);
  return v;
}
__device__ __forceinline__ unsigned short f2bf(float f){
  unsigned b = __float_as_uint(f);
  unsigned r = (b + 0x7FFFu + ((b >> 16) & 1u)) >> 16;
  return (unsigned short)r;
}
__device__ __forceinline__ float bf2f(unsigned short u){
  return __uint_as_float(((unsigned)u) << 16);
}

// ---------------- setup ----------------
__global__ __launch_bounds__(256) void k_set_member(const int* __restrict__ idx, int* __restrict__ member, int n){
  int i = blockIdx.x*256 + threadIdx.x;
  if (i < n) member[idx[i]] = 1;
}

__global__ __launch_bounds__(256) void k_build_list(int* __restrict__ member, int* __restrict__ mlist,
                                                    int* __restrict__ mcount, int N){
  int n = blockIdx.x*256 + threadIdx.x;
  if (n < N && member[n]) {
    int p = atomicAdd(mcount, 1);
    mlist[p] = n;
    member[n] = p + 2;   // slot+2 (0 = non-member)
  }
}

// record build + padded-counter degree counts + CSR ranks + fused ne-copy
__global__ __launch_bounds__(256) void k_count_rec(const int* __restrict__ sl, const int* __restrict__ member,
    ull* __restrict__ rec, ushort2* __restrict__ ranks,
    int* __restrict__ cnt_hed, int* __restrict__ cnt_slot, int E,
    const float4* __restrict__ csrc, float4* __restrict__ cdst, int ncopy){
  int gid = blockIdx.x*256 + threadIdx.x;
  int e = gid;
  bool valid = false;
  int r1 = 0, r2 = 0;
  if (e < E){
    int src = sl[3*e];
    int m = member[src];
    if (m){
      valid = true;
      int slot = m - 2;
      int hed = sl[3*e+1];
      int sem = sl[3*e+2];
      unsigned lo = (unsigned)slot | ((unsigned)sem << 20);
      rec[e] = (ull)lo | ((ull)(unsigned)hed << 32);
      r1 = atomicAdd(&cnt_hed[hed << 4], 1);
      r2 = atomicAdd(&cnt_slot[slot << 4], 1);
    } else {
      rec[e] = (ull)SENT << 32;
    }
  }
  // independent copy work overlaps the atomic-return latency
  int nthreads = gridDim.x * 256;
  for (int i = gid; i < ncopy; i += nthreads) cdst[i] = csrc[i];
  if (valid){
    ushort2 rk; rk.x = (unsigned short)r1; rk.y = (unsigned short)r2;
    ranks[e] = rk;
  }
}

// exclusive scan over stride-16 padded counters (dense output)
__global__ __launch_bounds__(256) void k_scan1(const int* __restrict__ in, int* __restrict__ out, int n,
                                               int* __restrict__ partials){
  __shared__ int s[256];
  int b = blockIdx.x, t = threadIdx.x;
  int base = b*2048 + t*8;
  int v[8]; int sum = 0;
  #pragma unroll
  for (int j=0;j<8;j++){ int i = base + j; v[j] = (i<n) ? in[(size_t)i << 4] : 0; sum += v[j]; }
  s[t] = sum;
  __syncthreads();
  for (int o=1;o<256;o<<=1){
    int x = (t>=o) ? s[t-o] : 0;
    __syncthreads();
    s[t] += x;
    __syncthreads();
  }
  int excl = s[t] - sum;
  if (t == 255) partials[b] = s[255];
  int run = excl;
  #pragma unroll
  for (int j=0;j<8;j++){ int i = base + j; if (i<n) out[i] = run; run += v[j]; }
}

__global__ void k_scan2(int* __restrict__ partials, int nb, int* __restrict__ out, int n){
  if (threadIdx.x==0 && blockIdx.x==0){
    int run = 0;
    for (int i=0;i<nb;i++){ int x = partials[i]; partials[i] = run; run += x; }
    out[n] = run;
  }
}

__global__ __launch_bounds__(256) void k_scan3(int* __restrict__ out, const int* __restrict__ partials, int n){
  int i = blockIdx.x*256 + threadIdx.x;
  if (i < n) out[i] += partials[i >> 11];
}

// atomic-free windowed scatter: p = off[key] + rank (4 windows for write locality)
__global__ __launch_bounds__(256) void k_scatter_both(const ull* __restrict__ rec,
    const ushort2* __restrict__ ranks, const int* __restrict__ mcountp,
    const int* __restrict__ off_hed, unsigned* __restrict__ edge_hed,
    const int* __restrict__ off_slot, unsigned* __restrict__ edge_src, int E){
  int w = blockIdx.x & 3;
  int chunk = blockIdx.x >> 2;
  int nchunk = gridDim.x >> 2;
  int per = (E + nchunk - 1) / nchunk;
  int lo_i = chunk * per;
  int hi_i = min(E, lo_i + per);
  int divs = (*mcountp + 3) >> 2;
  for (int i = lo_i + threadIdx.x; i < hi_i; i += 256){
    ull r = rec[i];
    unsigned hed = (unsigned)(r >> 32);
    if (hed == SENT) continue;
    unsigned lo = (unsigned)r;
    int slot = lo & 0xFFFFF;
    ushort2 rk = ranks[i];
    if ((int)hed / 5000 == w){
      edge_hed[off_hed[hed] + rk.x] = lo;
    }
    if (slot / divs == w){
      edge_src[off_slot[slot] + rk.y] = hed | (lo & 0xFFF00000u);
    }
  }
}

// ================= 4x4 register-blocked GEMM64 =================
#define LOAD_W(Wl, Wsrc) for (int i_=threadIdx.x; i_<1024; i_+=256) ((float4*)Wl)[i_] = ((const float4*)(Wsrc))[i_];

#define STAGE_AT(At, ro, nrows, LOADEXPR)                              \
  {                                                                    \
    int cg_ = threadIdx.x & 15, rl_ = threadIdx.x >> 4;                \
    for (int p_ = 0; p_ < 4; ++p_){                                    \
      int rloc_ = p_*16 + rl_;                                         \
      int r_ = (ro) + rloc_;                                           \
      float4 v_ = make_float4(0.f,0.f,0.f,0.f);                        \
      if (r_ < (nrows)){ v_ = (LOADEXPR); }                            \
      At[cg_*4+0][rloc_] = v_.x;                                       \
      At[cg_*4+1][rloc_] = v_.y;                                       \
      At[cg_*4+2][rloc_] = v_.z;                                       \
      At[cg_*4+3][rloc_] = v_.w;                                       \
    }                                                                  \
  }

__device__ __forceinline__ void gemm44(const float* __restrict__ Wl, const float (*At)[ATP],
                                       int rg4, int cg4, float4 acc[4]){
  #pragma unroll 8
  for (int k = 0; k < 64; ++k){
    const float4 w = *(const float4*)&Wl[k*64 + cg4];
    const float4 a = *(const float4*)&At[k][rg4];
    acc[0].x = fmaf(a.x,w.x,acc[0].x); acc[0].y = fmaf(a.x,w.y,acc[0].y);
    acc[0].z = fmaf(a.x,w.z,acc[0].z); acc[0].w = fmaf(a.x,w.w,acc[0].w);
    acc[1].x = fmaf(a.y,w.x,acc[1].x); acc[1].y = fmaf(a.y,w.y,acc[1].y);
    acc[1].z = fmaf(a.y,w.z,acc[1].z); acc[1].w = fmaf(a.y,w.w,acc[1].w);
    acc[2].x = fmaf(a.z,w.x,acc[2].x); acc[2].y = fmaf(a.z,w.y,acc[2].y);
    acc[2].z = fmaf(a.z,w.z,acc[2].z); acc[2].w = fmaf(a.z,w.w,acc[2].w);
    acc[3].x = fmaf(a.w,w.x,acc[3].x); acc[3].y = fmaf(a.w,w.y,acc[3].y);
    acc[3].z = fmaf(a.w,w.z,acc[3].z); acc[3].w = fmaf(a.w,w.w,acc[3].w);
  }
}

#define ZERO4(a) { a[0]=make_float4(0,0,0,0); a[1]=make_float4(0,0,0,0); a[2]=make_float4(0,0,0,0); a[3]=make_float4(0,0,0,0); }

// rowmatA: nm_bf = bf16(ne[mlist]@Wm) ; inner1 = ne[mlist]@Wi1
__global__ __launch_bounds__(256) void k_rowmatA(const float* __restrict__ ne, const float* __restrict__ Wm,
    const float* __restrict__ Wi1, const int* __restrict__ mlist, const int* __restrict__ mcountp,
    unsigned short* __restrict__ nm_bf, float* __restrict__ inner1){
  __shared__ float W1[4096], W2[4096];
  __shared__ float At[64][ATP];
  int t = threadIdx.x;
  int nrows = *mcountp;
  int ntiles = (nrows + 63) >> 6;
  LOAD_W(W1, Wm)
  LOAD_W(W2, Wi1)
  int cg4 = (t & 15)*4, rg4 = (t >> 4)*4;
  for (int tile = blockIdx.x; tile < ntiles; tile += gridDim.x){
    int ro = tile << 6;
    __syncthreads();
    STAGE_AT(At, ro, nrows, (*(const float4*)&ne[(size_t)mlist[r_]*64 + cg_*4]))
    __syncthreads();
    float4 a1[4]; ZERO4(a1)
    float4 a2[4]; ZERO4(a2)
    #pragma unroll 4
    for (int k = 0; k < 64; ++k){
      const float4 w1 = *(const float4*)&W1[k*64 + cg4];
      const float4 w2 = *(const float4*)&W2[k*64 + cg4];
      const float4 a  = *(const float4*)&At[k][rg4];
      a1[0].x=fmaf(a.x,w1.x,a1[0].x); a1[0].y=fmaf(a.x,w1.y,a1[0].y); a1[0].z=fmaf(a.x,w1.z,a1[0].z); a1[0].w=fmaf(a.x,w1.w,a1[0].w);
      a1[1].x=fmaf(a.y,w1.x,a1[1].x); a1[1].y=fmaf(a.y,w1.y,a1[1].y); a1[1].z=fmaf(a.y,w1.z,a1[1].z); a1[1].w=fmaf(a.y,w1.w,a1[1].w);
      a1[2].x=fmaf(a.z,w1.x,a1[2].x); a1[2].y=fmaf(a.z,w1.y,a1[2].y); a1[2].z=fmaf(a.z,w1.z,a1[2].z); a1[2].w=fmaf(a.z,w1.w,a1[2].w);
      a1[3].x=fmaf(a.w,w1.x,a1[3].x); a1[3].y=fmaf(a.w,w1.y,a1[3].y); a1[3].z=fmaf(a.w,w1.z,a1[3].z); a1[3].w=fmaf(a.w,w1.w,a1[3].w);
      a2[0].x=fmaf(a.x,w2.x,a2[0].x); a2[0].y=fmaf(a.x,w2.y,a2[0].y); a2[0].z=fmaf(a.x,w2.z,a2[0].z); a2[0].w=fmaf(a.x,w2.w,a2[0].w);
      a2[1].x=fmaf(a.y,w2.x,a2[1].x); a2[1].y=fmaf(a.y,w2.y,a2[1].y); a2[1].z=fmaf(a.y,w2.z,a2[1].z); a2[1].w=fmaf(a.y,w2.w,a2[1].w);
      a2[2].x=fmaf(a.z,w2.x,a2[2].x); a2[2].y=fmaf(a.z,w2.y,a2[2].y); a2[2].z=fmaf(a.z,w2.z,a2[2].z); a2[2].w=fmaf(a.z,w2.w,a2[2].w);
      a2[3].x=fmaf(a.w,w2.x,a2[3].x); a2[3].y=fmaf(a.w,w2.y,a2[3].y); a2[3].z=fmaf(a.w,w2.z,a2[3].z); a2[3].w=fmaf(a.w,w2.w,a2[3].w);
    }
    #pragma unroll
    for (int i = 0; i < 4; ++i){
      int r = ro + rg4 + i;
      if (r < nrows){
        ushort4 s;
        s.x = f2bf(a1[i].x); s.y = f2bf(a1[i].y); s.z = f2bf(a1[i].z); s.w = f2bf(a1[i].w);
        *(ushort4*)&nm_bf[(size_t)r*64 + cg4] = s;
        *(float4*)&inner1[(size_t)r*64 + cg4] = a2[i];
      }
    }
  }
}

// rowmatB: hq = he@Wa ; block 0 prologue: smbuf = sema@Wm
__global__ __launch_bounds__(256) void k_rowmatB(const float* __restrict__ he, const float* __restrict__ sema,
    const float* __restrict__ Wa, const float* __restrict__ Wm,
    float* __restrict__ hq, float* __restrict__ smbuf, int H, int NS_){
  __shared__ float W1[4096];
  __shared__ float At[64][ATP];
  int t = threadIdx.x;
  if (blockIdx.x == 0 && t < 160){
    int sr = t >> 4, c4 = (t & 15)*4;
    float4 accs = make_float4(0,0,0,0);
    #pragma unroll 8
    for (int k = 0; k < 64; ++k){
      float a = sema[sr*64 + k];
      float4 w = *(const float4*)&Wm[k*64 + c4];
      accs.x = fmaf(a,w.x,accs.x); accs.y = fmaf(a,w.y,accs.y);
      accs.z = fmaf(a,w.z,accs.z); accs.w = fmaf(a,w.w,accs.w);
    }
    *(float4*)&smbuf[(size_t)sr*64 + c4] = accs;
  }
  LOAD_W(W1, Wa)
  int nrows = H;
  int ntiles = (nrows + 63) >> 6;
  int cg4 = (t & 15)*4, rg4 = (t >> 4)*4;
  for (int tile = blockIdx.x; tile < ntiles; tile += gridDim.x){
    int ro = tile << 6;
    __syncthreads();
    STAGE_AT(At, ro, nrows, (*(const float4*)&he[(size_t)r_*64 + cg_*4]))
    __syncthreads();
    float4 acc[4]; ZERO4(acc)
    gemm44(W1, At, rg4, cg4, acc);
    #pragma unroll
    for (int i = 0; i < 4; ++i){
      int r = ro + rg4 + i;
      if (r < nrows) *(float4*)&hq[(size_t)r*64 + cg4] = acc[i];
    }
  }
}

// matfuse (unchanged)
__global__ __launch_bounds__(256) void k_matfuse(const float* __restrict__ inner1, const float* __restrict__ nagg,
    const float* __restrict__ oagg, const float* __restrict__ Wi2, const float* __restrict__ Wn,
    const float* __restrict__ We, const float* __restrict__ Ws,
    const int* __restrict__ mlist, const int* __restrict__ mcountp, float* __restrict__ ne){
  __shared__ float Wl[4096];
  __shared__ float At[64][ATP];
  int t = threadIdx.x;
  int cnt = *mcountp;
  int ntiles = (cnt + 63) >> 6;
  int cg4 = (t & 15)*4, rg4 = (t >> 4)*4;
  for (int tile = blockIdx.x; tile < ntiles; tile += gridDim.x){
    int ro = tile << 6;
    __syncthreads();
    STAGE_AT(At, ro, cnt, (*(const float4*)&nagg[(size_t)r_*64 + cg_*4]))
    LOAD_W(Wl, Ws)
    __syncthreads();
    float4 acc[4]; ZERO4(acc)
    gemm44(Wl, At, rg4, cg4, acc);   // acc = An@Ws
    __syncthreads();
    LOAD_W(Wl, Wi2)
    __syncthreads();
    float4 p1[4]; ZERO4(p1)
    gemm44(Wl, At, rg4, cg4, p1);    // p1 = An@Wi2
    float x[4][4];
    #pragma unroll
    for (int i = 0; i < 4; ++i){
      int r = ro + rg4 + i;
      float4 v = make_float4(0.f,0.f,0.f,0.f);
      if (r < cnt) v = *(const float4*)&inner1[(size_t)r*64 + cg4];
      float x0 = p1[i].x + v.x, x1 = p1[i].y + v.y, x2 = p1[i].z + v.z, x3 = p1[i].w + v.w;
      x[i][0] = x0 >= 0.f ? x0 : 0.01f*x0;
      x[i][1] = x1 >= 0.f ? x1 : 0.01f*x1;
      x[i][2] = x2 >= 0.f ? x2 : 0.01f*x2;
      x[i][3] = x3 >= 0.f ? x3 : 0.01f*x3;
    }
    __syncthreads();
    #pragma unroll
    for (int i = 0; i < 4; ++i)
      #pragma unroll
      for (int j = 0; j < 4; ++j)
        At[cg4+j][rg4+i] = x[i][j];
    LOAD_W(Wl, Wn)
    __syncthreads();
    gemm44(Wl, At, rg4, cg4, acc);   // acc += Ai@Wn
    __syncthreads();
    STAGE_AT(At, ro, cnt, (*(const float4*)&oagg[(size_t)r_*64 + cg_*4]))
    LOAD_W(Wl, We)
    __syncthreads();
    gemm44(Wl, At, rg4, cg4, acc);   // acc += Ao@We
    #pragma unroll
    for (int i = 0; i < 4; ++i){
      int r = ro + rg4 + i;
      if (r < cnt){
        float4 o = make_float4(tanhf(acc[i].x), tanhf(acc[i].y), tanhf(acc[i].z), tanhf(acc[i].w));
        *(float4*)&ne[(size_t)mlist[r]*64 + cg4] = o;
      }
    }
  }
}

// ---------------- attention + W_upd matvec fused; bf16 nm gathers ----------------
__global__ __launch_bounds__(256) void k_attn_upd(const int* __restrict__ off_hed, const unsigned* __restrict__ edge_hed,
    const unsigned short* __restrict__ nm_bf, const float* __restrict__ smb, const float* __restrict__ hq,
    const float* __restrict__ W, const float* __restrict__ he_cur, float* __restrict__ he_next,
    unsigned short* __restrict__ he_bf, int H){
  __shared__ float Wl[4096];
  __shared__ float sm_lds[640];
  __shared__ float aggl[256];
  int t = threadIdx.x;
  for (int i=t;i<1024;i+=256) ((float4*)Wl)[i] = ((const float4*)W)[i];
  for (int i=t;i<640;i+=256) sm_lds[i] = smb[i];
  __syncthreads();
  int w = t >> 6, lane = t & 63;
  int nhb = (H + 3) >> 2;
  for (int hb = blockIdx.x; hb < nhb; hb += gridDim.x){
    int h = hb*4 + w;
    if (h >= H) continue;
    int start = off_hed[h], end = off_hed[h+1];
    if (start == end){
      float v = he_cur[(size_t)h*64 + lane];
      he_next[(size_t)h*64 + lane] = v;
      he_bf[(size_t)h*64 + lane] = f2bf(v);
      continue;
    }
    int g = lane >> 4, dl = (lane & 15)*4;
    float4 q4 = *(const float4*)&hq[(size_t)h*64 + dl];
    float ax=0.f, ay=0.f, az=0.f, aw=0.f, dsum=0.f, m=-3.4e38f;
    for (int idx0 = start; idx0 < end; idx0 += 4){
      int idx = idx0 + g;
      bool valid = idx < end;
      unsigned u = valid ? edge_hed[idx] : 0u;
      int slot = u & 0xFFFFF, sem = u >> 20;
      float4 nm4 = make_float4(0.f,0.f,0.f,0.f);
      if (valid){
        ushort4 nu = *(const ushort4*)&nm_bf[(size_t)slot*64 + dl];
        nm4 = make_float4(bf2f(nu.x), bf2f(nu.y), bf2f(nu.z), bf2f(nu.w));
      }
      float4 sm4 = *(const float4*)&sm_lds[sem*64 + dl];
      float mkx = nm4.x+sm4.x, mky = nm4.y+sm4.y, mkz = nm4.z+sm4.z, mkw = nm4.w+sm4.w;
      float part = mkx*q4.x + mky*q4.y + mkz*q4.z + mkw*q4.w;
      part = group16_sum(part);
      float l = valid ? part : -3.4e38f;
      float mn = fmaxf(m, l);
      float scale = __expf(m - mn);
      float wgt = valid ? __expf(l - mn) : 0.f;
      ax = ax*scale + wgt*mkx; ay = ay*scale + wgt*mky;
      az = az*scale + wgt*mkz; aw = aw*scale + wgt*mkw;
      dsum = dsum*scale + wgt;
      m = mn;
    }
    float mg = fmaxf(m, __shfl_xor(m, 16, 64));
    mg = fmaxf(mg, __shfl_xor(mg, 32, 64));
    float cs = __expf(m - mg);
    ax*=cs; ay*=cs; az*=cs; aw*=cs; dsum*=cs;
    ax = xgroup_sum(ax); ay = xgroup_sum(ay); az = xgroup_sum(az); aw = xgroup_sum(aw);
    dsum = xgroup_sum(dsum);
    if (lane < 16){
      float inv = 1.f/(dsum + EPSF);
      aggl[w*64 + dl+0] = ax*inv;
      aggl[w*64 + dl+1] = ay*inv;
      aggl[w*64 + dl+2] = az*inv;
      aggl[w*64 + dl+3] = aw*inv;
    }
    float o = 0.f;
    #pragma unroll 8
    for (int j=0;j<64;j++) o = fmaf(aggl[w*64 + j], Wl[j*64 + lane], o);
    float ov = tanhf(o);
    he_next[(size_t)h*64 + lane] = ov;
    he_bf[(size_t)h*64 + lane] = f2bf(ov);
  }
}

// ---------------- per-member-slot aggregation; bf16 he gathers ----------------
__global__ __launch_bounds__(256) void k_nodeagg2(const int* __restrict__ mcountp,
    const int* __restrict__ off_slot, const unsigned* __restrict__ edge_src,
    const unsigned short* __restrict__ he_bf, const float* __restrict__ sema,
    float* __restrict__ nagg, float* __restrict__ oagg){
  __shared__ float sm_lds[640];
  int t = threadIdx.x;
  for (int i=t;i<640;i+=256) sm_lds[i] = sema[i];
  __syncthreads();
  int w = t >> 6, lane = t & 63;
  int mc = *mcountp;
  int npb = (mc + 3) >> 2;
  int g = lane >> 4, dl = (lane & 15)*4;
  for (int pb = blockIdx.x; pb < npb; pb += gridDim.x){
    int p = pb*4 + w;
    if (p >= mc) continue;
    int start = off_slot[p], end = off_slot[p+1];
    float anx=0.f, any_=0.f, anz=0.f, anw=0.f;
    float aox=0.f, aoy=0.f, aoz=0.f, aow=0.f;
    for (int idx0 = start; idx0 < end; idx0 += 4){
      int idx = idx0 + g;
      if (idx < end){
        unsigned u = edge_src[idx];
        int hd = u & 0xFFFFF, sem = u >> 20;
        ushort4 hu = *(const ushort4*)&he_bf[(size_t)hd*64 + dl];
        float4 hv = make_float4(bf2f(hu.x), bf2f(hu.y), bf2f(hu.z), bf2f(hu.w));
        float4 sv = *(const float4*)&sm_lds[sem*64 + dl];
        anx += hv.x; any_ += hv.y; anz += hv.z; anw += hv.w;
        aox = fmaf(hv.x, sv.x, aox); aoy = fmaf(hv.y, sv.y, aoy);
        aoz = fmaf(hv.z, sv.z, aoz); aow = fmaf(hv.w, sv.w, aow);
      }
    }
    anx = xgroup_sum(anx); any_ = xgroup_sum(any_); anz = xgroup_sum(anz); anw = xgroup_sum(anw);
    aox = xgroup_sum(aox); aoy = xgroup_sum(aoy); aoz = xgroup_sum(aoz); aow = xgroup_sum(aow);
    if (lane < 16){
      float inv = 1.f/((float)(end - start) + EPSF);
      *(float4*)&nagg[(size_t)p*64 + dl] = make_float4(anx*inv, any_*inv, anz*inv, anw*inv);
      *(float4*)&oagg[(size_t)p*64 + dl] = make_float4(aox*inv, aoy*inv, aoz*inv, aow*inv);
    }
  }
}

extern "C" void kernel_launch(void* const* d_in, const int* in_sizes, int n_in,
                              void* d_out, int out_size, void* d_ws, size_t ws_size,
                              hipStream_t stream)
{
  (void)in_sizes; (void)n_in; (void)out_size; (void)ws_size;
  const float* node_emb  = (const float*)d_in[0];
  const float* hyper_emb = (const float*)d_in[1];
  const float* sema_emb  = (const float*)d_in[2];
  const float* W_msg = (const float*)d_in[3];
  const float* W_att = (const float*)d_in[4];
  const float* W_upd = (const float*)d_in[5];
  const float* Wi1   = (const float*)d_in[6];
  const float* Wi2   = (const float*)d_in[7];
  const float* Wo_n  = (const float*)d_in[8];
  const float* Wo_e  = (const float*)d_in[9];
  const float* Wo_s  = (const float*)d_in[10];
  const int* node_indices = (const int*)d_in[11];
  const int* semalinks    = (const int*)d_in[14];

  constexpr int N = 100000, H = 20000, NS = 10, L = 2, E = 1000000, NB = 50000;

  float* out_ne = (float*)d_out;                    // N*64
  float* out_he = (float*)d_out + (size_t)N*64;     // H*64

  char* wsp = (char*)d_ws;
  auto alloc = [&](size_t bytes)->char*{ char* p = wsp; wsp += (bytes + 255) & ~(size_t)255; return p; };
  char* zstart = wsp;
  int* member   = (int*)alloc((size_t)N*4);
  int* cnt_hed  = (int*)alloc((size_t)H*CPAD*4);     // padded: 1 counter / 64B line
  int* cnt_slot = (int*)alloc((size_t)NSLOT*CPAD*4);
  int* mcount   = (int*)alloc(256);
  size_t zbytes = (size_t)(wsp - zstart);
  int* off_hed   = (int*)alloc((size_t)(H+1)*4);
  int* off_slot  = (int*)alloc((size_t)(NSLOT+1)*4);
  int* mlist     = (int*)alloc((size_t)NB*4);
  int* partials  = (int*)alloc(256);
  ull* rec       = (ull*)alloc((size_t)E*8);
  ushort2* ranks = (ushort2*)alloc((size_t)E*4);
  unsigned* edge_hed = (unsigned*)alloc((size_t)E*4);
  unsigned* edge_src = (unsigned*)alloc((size_t)E*4);
  float* smbuf  = (float*)alloc((size_t)NS*64*4);
  float* hq     = (float*)alloc((size_t)H*64*4);
  unsigned short* nm_bf = (unsigned short*)alloc((size_t)NB*64*2);
  unsigned short* he_bf = (unsigned short*)alloc((size_t)H*64*2);
  float* he1    = (float*)alloc((size_t)H*64*4);
  float* naggb  = (float*)alloc((size_t)NB*64*4);
  float* oaggb  = (float*)alloc((size_t)NB*64*4);
  float* inner1 = (float*)alloc((size_t)NB*64*4);

  hipMemsetAsync(zstart, 0, zbytes, stream);

  k_set_member<<<(NB+255)/256, 256, 0, stream>>>(node_indices, member, NB);
  k_build_list<<<(N+255)/256, 256, 0, stream>>>(member, mlist, mcount, N);
  k_count_rec<<<(E+255)/256, 256, 0, stream>>>(semalinks, member, rec, ranks, cnt_hed, cnt_slot, E,
                                               (const float4*)node_emb, (float4*)out_ne, N*64/4);

  int nb_h = (H + 2047)/2048, nb_s = (NSLOT + 2047)/2048;
  k_scan1<<<nb_h, 256, 0, stream>>>(cnt_hed, off_hed, H, partials);
  k_scan2<<<1, 64, 0, stream>>>(partials, nb_h, off_hed, H);
  k_scan3<<<(H+255)/256, 256, 0, stream>>>(off_hed, partials, H);
  k_scan1<<<nb_s, 256, 0, stream>>>(cnt_slot, off_slot, NSLOT, partials);
  k_scan2<<<1, 64, 0, stream>>>(partials, nb_s, off_slot, NSLOT);
  k_scan3<<<(NSLOT+255)/256, 256, 0, stream>>>(off_slot, partials, NSLOT);

  k_scatter_both<<<2048, 256, 0, stream>>>(rec, ranks, mcount, off_hed, edge_hed,
                                           off_slot, edge_src, E);

  for (int i = 0; i < L; ++i){
    const float* Wm = W_msg + (size_t)i*4096;
    const float* Wa = W_att + (size_t)i*4096;
    const float* Wu = W_upd + (size_t)i*4096;
    const float* wi1 = Wi1 + (size_t)i*4096;
    const float* wi2 = Wi2 + (size_t)i*4096;
    const float* won = Wo_n + (size_t)i*4096;
    const float* woe = Wo_e + (size_t)i*4096;
    const float* wos = Wo_s + (size_t)i*4096;
    const float* he_cur = (i == 0) ? hyper_emb : he1;
    float* he_next = (i == 0) ? he1 : out_he;

    k_rowmatA<<<800, 256, 0, stream>>>(out_ne, Wm, wi1, mlist, mcount, nm_bf, inner1);
    k_rowmatB<<<320, 256, 0, stream>>>(he_cur, sema_emb, Wa, Wm, hq, smbuf, H, NS);
    k_attn_upd<<<2048, 256, 0, stream>>>(off_hed, edge_hed, nm_bf, smbuf, hq, Wu,
                                         he_cur, he_next, he_bf, H);
    k_nodeagg2<<<2048, 256, 0, stream>>>(mcount, off_slot, edge_src, he_bf, sema_emb, naggb, oaggb);
    k_matfuse<<<800, 256, 0, stream>>>(inner1, naggb, oaggb, wi2, won, woe, wos, mlist, mcount, out_ne);
  }
}